// Round 12
// baseline (2766.343 us; speedup 1.0000x reference)
//
#include <hip/hip_runtime.h>
#include <math.h>

typedef unsigned short ushort;
typedef __bf16 bf16x8 __attribute__((ext_vector_type(8)));
typedef float f32x4 __attribute__((ext_vector_type(4)));

// Problem dims
constexpr int Bb  = 8;
constexpr int Ss  = 512;
constexpr int Hh  = 768;
constexpr int Ll  = 12;
constexpr int NHh = 12;
constexpr int Ff  = 3072;
constexpr int Vv  = 21128;
constexpr int DHh = 64;
constexpr int Mm  = Bb * Ss;   // 4096
constexpr int SEP_ID = 102;
constexpr int VP  = 21504;     // vocab padded to 168*128
constexpr int NCH = 42;        // vocab chunks (cls grid x)
constexpr int TPC = 4;         // 128-col tiles per chunk
constexpr int QKVN = 3 * Hh;   // 2304
constexpr float LSE_SHIFT = 20.0f;

static __device__ __forceinline__ ushort f2bf(float f) {
    unsigned u = __float_as_uint(f);
    unsigned r = (u + 0x7fffu + ((u >> 16) & 1u)) >> 16;
    return (ushort)r;
}
static __device__ __forceinline__ float bf2f(unsigned x) {
    return __uint_as_float(x << 16);
}

// ---------------------------------------------------------------------------
// 1. Find first SEP per batch
// ---------------------------------------------------------------------------
__global__ __launch_bounds__(512) void sep_kernel(const int* __restrict__ ids,
                                                  int* __restrict__ info)
{
    int b = blockIdx.x;
    int t = threadIdx.x;
    int v = (ids[b * Ss + t] == SEP_ID) ? t : 0x7FFFFFFF;
    #pragma unroll
    for (int off = 32; off; off >>= 1) {
        int o = __shfl_xor(v, off);
        v = min(v, o);
    }
    __shared__ int wmin[8];
    int lane = t & 63, wid = t >> 6;
    if (lane == 0) wmin[wid] = v;
    __syncthreads();
    if (t == 0) {
        int first = wmin[0];
        #pragma unroll
        for (int w = 1; w < 8; w++) first = min(first, wmin[w]);
        int has = (first != 0x7FFFFFFF) ? 1 : 0;
        info[b * 4 + 0] = first;
        info[b * 4 + 1] = has;
        info[b * 4 + 2] = has ? min(first, Ss - 2) : (Ss + 1);
    }
}

// ---------------------------------------------------------------------------
// 2. Embedding + LayerNorm -> fp32 x and bf16 xb
// ---------------------------------------------------------------------------
__global__ __launch_bounds__(256) void embed_ln_kernel(
    const int* __restrict__ ids, const float* __restrict__ we,
    const float* __restrict__ pe, const float* __restrict__ te,
    const float* __restrict__ g, const float* __restrict__ bp,
    float* __restrict__ x, ushort* __restrict__ xb)
{
    int tok = blockIdx.x;
    int s = tok & (Ss - 1);
    int tid = threadIdx.x;
    int id = ids[tok];
    float e[3];
    #pragma unroll
    for (int r = 0; r < 3; r++) {
        int h = tid + (r << 8);
        e[r] = we[(size_t)id * Hh + h] + pe[(size_t)s * Hh + h] + te[h];
    }
    float sum = e[0] + e[1] + e[2];
    float sq  = fmaf(e[0], e[0], fmaf(e[1], e[1], e[2] * e[2]));
    #pragma unroll
    for (int off = 32; off; off >>= 1) {
        sum += __shfl_xor(sum, off);
        sq  += __shfl_xor(sq, off);
    }
    __shared__ float red[8];
    int lane = tid & 63, wid = tid >> 6;
    if (lane == 0) { red[wid] = sum; red[4 + wid] = sq; }
    __syncthreads();
    sum = red[0] + red[1] + red[2] + red[3];
    sq  = red[4] + red[5] + red[6] + red[7];
    float mean = sum * (1.0f / Hh);
    float var  = sq * (1.0f / Hh) - mean * mean;
    float rstd = rsqrtf(var + 1e-12f);
    #pragma unroll
    for (int r = 0; r < 3; r++) {
        int h = tid + (r << 8);
        float v = (e[r] - mean) * rstd * g[h] + bp[h];
        x[(size_t)tok * Hh + h] = v;
        xb[(size_t)tok * Hh + h] = f2bf(v);
    }
}

// ---------------------------------------------------------------------------
// 3. Residual + 4 split-K bf16 partials + bias + LayerNorm
// ---------------------------------------------------------------------------
__global__ __launch_bounds__(256) void resid_ln4_kernel(
    const float* __restrict__ resid, const ushort* __restrict__ p,  // [4][Mm][Hh] bf16
    const float* __restrict__ bias, const float* __restrict__ g,
    const float* __restrict__ bp,
    float* __restrict__ out, ushort* __restrict__ outb)
{
    const size_t MHl = (size_t)Mm * Hh;
    int tok = blockIdx.x;
    int tid = threadIdx.x;
    float e[3];
    #pragma unroll
    for (int r = 0; r < 3; r++) {
        int h = tid + (r << 8);
        size_t idx = (size_t)tok * Hh + h;
        float acc = resid[idx] + bias[h];
        acc += bf2f(p[idx]);
        acc += bf2f(p[MHl + idx]);
        acc += bf2f(p[2 * MHl + idx]);
        acc += bf2f(p[3 * MHl + idx]);
        e[r] = acc;
    }
    float sum = e[0] + e[1] + e[2];
    float sq  = fmaf(e[0], e[0], fmaf(e[1], e[1], e[2] * e[2]));
    #pragma unroll
    for (int off = 32; off; off >>= 1) {
        sum += __shfl_xor(sum, off);
        sq  += __shfl_xor(sq, off);
    }
    __shared__ float red[8];
    int lane = tid & 63, wid = tid >> 6;
    if (lane == 0) { red[wid] = sum; red[4 + wid] = sq; }
    __syncthreads();
    sum = red[0] + red[1] + red[2] + red[3];
    sq  = red[4] + red[5] + red[6] + red[7];
    float mean = sum * (1.0f / Hh);
    float var  = sq * (1.0f / Hh) - mean * mean;
    float rstd = rsqrtf(var + 1e-12f);
    #pragma unroll
    for (int r = 0; r < 3; r++) {
        int h = tid + (r << 8);
        float v = (e[r] - mean) * rstd * g[h] + bp[h];
        out[(size_t)tok * Hh + h] = v;
        outb[(size_t)tok * Hh + h] = f2bf(v);
    }
}

// ---------------------------------------------------------------------------
// 4. Fused per-layer weight prep: 4 HxH + HxF + FxH transposes + bias concat
// ---------------------------------------------------------------------------
__global__ __launch_bounds__(256) void prep_kernel(
    const float* __restrict__ Wq, const float* __restrict__ Wk,
    const float* __restrict__ Wv, const float* __restrict__ Wo,
    const float* __restrict__ W1, const float* __restrict__ W2,
    const float* __restrict__ bq, const float* __restrict__ bk,
    const float* __restrict__ bv,
    ushort* __restrict__ qkvoT, ushort* __restrict__ w1T,
    ushort* __restrict__ w2T, float* __restrict__ bqkv)
{
    int b = blockIdx.x;
    if (b >= 6912) {   // bias concat
        for (int j = threadIdx.x; j < Hh; j += 256) {
            bqkv[j]          = bq[j];
            bqkv[Hh + j]     = bk[j];
            bqkv[2 * Hh + j] = bv[j];
        }
        return;
    }
    const float* W;
    ushort* Wt;
    int K, N, n0, k0;
    if (b < 2304) {          // QKVO: 4 x 576 tiles of HxH
        int which = b / 576, t = b % 576;
        const float* srcs[4] = { Wq, Wk, Wv, Wo };
        W = srcs[which];
        Wt = qkvoT + (size_t)which * Hh * Hh;
        K = Hh; N = Hh;
        n0 = (t % 24) * 32; k0 = (t / 24) * 32;
    } else if (b < 4608) {   // W1: [Hh][Ff] -> w1T [Ff][Hh]
        int t = b - 2304;
        W = W1; Wt = w1T; K = Hh; N = Ff;
        n0 = (t % 96) * 32; k0 = (t / 96) * 32;
    } else {                 // W2: [Ff][Hh] -> w2T [Hh][Ff]
        int t = b - 4608;
        W = W2; Wt = w2T; K = Ff; N = Hh;
        n0 = (t % 24) * 32; k0 = (t / 24) * 32;
    }
    __shared__ float ts[32][33];
    int tx = threadIdx.x & 31, ty = threadIdx.x >> 5;
    #pragma unroll
    for (int i = 0; i < 32; i += 8)
        ts[ty + i][tx] = W[(size_t)(k0 + ty + i) * N + n0 + tx];
    __syncthreads();
    #pragma unroll
    for (int i = 0; i < 32; i += 8)
        Wt[(size_t)(n0 + ty + i) * K + k0 + tx] = f2bf(ts[tx][ty + i]);
}

// 4b. Padded transpose + bias pad for classifier
__global__ __launch_bounds__(256) void pad_transpose_kernel(
    const float* __restrict__ W, ushort* __restrict__ Wt, int K, int N)
{
    __shared__ float ts[32][33];
    int n0 = blockIdx.x * 32, k0 = blockIdx.y * 32;
    int tx = threadIdx.x & 31, ty = threadIdx.x >> 5;
    #pragma unroll
    for (int i = 0; i < 32; i += 8) {
        int n = n0 + tx;
        ts[ty + i][tx] = (n < N) ? W[(size_t)(k0 + ty + i) * N + n] : 0.f;
    }
    __syncthreads();
    #pragma unroll
    for (int i = 0; i < 32; i += 8)
        Wt[(size_t)(n0 + ty + i) * K + k0 + tx] = f2bf(ts[tx][ty + i]);
}

__global__ __launch_bounds__(256) void bias_pad_kernel(
    const float* __restrict__ cb, float* __restrict__ cbp)
{
    int i = blockIdx.x * 256 + threadIdx.x;
    if (i < VP) cbp[i] = (i < Vv) ? cb[i] : -1.0e9f;
}

// ---------------------------------------------------------------------------
// 5. bf16 MFMA GEMM, BK=64 + XOR chunk swizzle.
//    Tile [128][64] = 1024 16B-chunks -> 4 staging rounds of 256 lanes
//    (r12 fix: was 2 rounds, leaving rows 64-127 unstaged -> NaN).
//    Linear LDS dest; SOURCE chunk pre-swizzled (^= row&7); READ swizzled.
// ---------------------------------------------------------------------------
template <int ACT, int OUT_BF, int BIAS>
__global__ __launch_bounds__(256) void mfma_gemm(
    const ushort* __restrict__ A,
    const ushort* __restrict__ Bt,
    const float* __restrict__ bias,
    void* __restrict__ C,
    int N, int K, int lda, int ldb)
{
    __shared__ __align__(16) ushort As[128 * 64];
    __shared__ __align__(16) ushort Bs[128 * 64];
    const int tid = threadIdx.x;
    const int lane = tid & 63, wid = tid >> 6;
    const int m0 = blockIdx.y * 128, n0 = blockIdx.x * 128;
    const int kbase = blockIdx.z * K;
    const size_t zoff = (size_t)blockIdx.z * Mm * N;
    A += kbase;
    Bt += kbase;
    const int wr = (wid >> 1) * 64, wc = (wid & 1) * 64;
    const int lr = lane & 15;
    const int hi = lane >> 4;

    f32x4 acc[4][4];
    #pragma unroll
    for (int mi = 0; mi < 4; ++mi)
        #pragma unroll
        for (int ni = 0; ni < 4; ++ni)
            acc[mi][ni] = (f32x4){0.f, 0.f, 0.f, 0.f};

    for (int k0 = 0; k0 < K; k0 += 64) {
        // Stage full [128][64] tiles: 1024 chunks each, 4 rounds.
        #pragma unroll
        for (int i = 0; i < 4; ++i) {
            int idx = i * 256 + tid;
            int r = idx >> 3;
            int cs = ((idx & 7) ^ (r & 7)) << 3;
            __builtin_amdgcn_global_load_lds(
                (const __attribute__((address_space(1))) void*)(A + (size_t)(m0 + r) * lda + k0 + cs),
                (__attribute__((address_space(3))) void*)(As + (size_t)(i * 256 + (wid << 6)) * 8),
                16, 0, 0);
        }
        #pragma unroll
        for (int i = 0; i < 4; ++i) {
            int idx = i * 256 + tid;
            int r = idx >> 3;
            int cs = ((idx & 7) ^ (r & 7)) << 3;
            __builtin_amdgcn_global_load_lds(
                (const __attribute__((address_space(1))) void*)(Bt + (size_t)(n0 + r) * ldb + k0 + cs),
                (__attribute__((address_space(3))) void*)(Bs + (size_t)(i * 256 + (wid << 6)) * 8),
                16, 0, 0);
        }
        __syncthreads();

        #pragma unroll
        for (int kk = 0; kk < 2; ++kk) {
            bf16x8 af[4], bfr[4];
            #pragma unroll
            for (int mi = 0; mi < 4; ++mi) {
                int row = wr + mi * 16 + lr;
                int pc = ((kk << 2) + hi) ^ (row & 7);   // swizzled read chunk
                af[mi] = *(const bf16x8*)(As + (size_t)row * 64 + (pc << 3));
            }
            #pragma unroll
            for (int ni = 0; ni < 4; ++ni) {
                int row = wc + ni * 16 + lr;
                int pc = ((kk << 2) + hi) ^ (row & 7);
                bfr[ni] = *(const bf16x8*)(Bs + (size_t)row * 64 + (pc << 3));
            }
            #pragma unroll
            for (int mi = 0; mi < 4; ++mi)
                #pragma unroll
                for (int ni = 0; ni < 4; ++ni)
                    acc[mi][ni] = __builtin_amdgcn_mfma_f32_16x16x32_bf16(
                        af[mi], bfr[ni], acc[mi][ni], 0, 0, 0);
        }
        __syncthreads();
    }

    #pragma unroll
    for (int ni = 0; ni < 4; ++ni) {
        int col = n0 + wc + ni * 16 + lr;
        float bsv = 0.f;
        if (BIAS) bsv = bias[col];
        #pragma unroll
        for (int mi = 0; mi < 4; ++mi) {
            f32x4 v = acc[mi][ni];
            #pragma unroll
            for (int q = 0; q < 4; ++q) {
                int row = m0 + wr + mi * 16 + (hi << 2) + q;
                float val = v[q] + bsv;
                if (ACT == 1) {
                    float y = 0.7978845608028654f
                              * (val + 0.044715f * val * val * val);
                    val = val / (1.0f + __expf(-2.0f * y));
                }
                if (OUT_BF)
                    ((ushort*)C)[zoff + (size_t)row * N + col] = f2bf(val);
                else
                    ((float*)C)[zoff + (size_t)row * N + col] = val;
            }
        }
    }
}

// ---------------------------------------------------------------------------
// 6. Fused MFMA flash attention (stride-72 conflict-free LDS)
// ---------------------------------------------------------------------------
constexpr int SP = 65;   // S_lds stride (f32)
constexpr int PS = 72;   // P_lds stride (u16)
constexpr int VS = 72;   // Vt_lds / K_lds stride (u16)

__global__ __launch_bounds__(256) void flash_attn_kernel(
    const ushort* __restrict__ qkv, const int* __restrict__ info,
    ushort* __restrict__ ctx)
{
    __shared__ __align__(16) ushort K_lds[64 * VS];
    __shared__ __align__(16) ushort Vt_lds[64 * VS];
    __shared__ __align__(16) ushort P_lds[64 * PS];
    __shared__ float S_lds[64 * SP];
    __shared__ float m_s[64], l_s[64], rf_s[64];

    const int tid = threadIdx.x;
    const int lane = tid & 63, wid = tid >> 6;
    const int bh = blockIdx.y, b = bh / NHh, h = bh % NHh;
    const int i0 = blockIdx.x * 64;
    const int lr = lane & 15, hi = lane >> 4;
    const int kg = hi << 3;
    const int wr = (wid >> 1) * 32;
    const int wc = (wid & 1) * 32;
    const int has = info[b * 4 + 1], sep = info[b * 4 + 2];
    const size_t tok0 = (size_t)b * Ss;

    bf16x8 qf[2][2];
    #pragma unroll
    for (int mi = 0; mi < 2; ++mi)
        #pragma unroll
        for (int kk = 0; kk < 2; ++kk)
            qf[mi][kk] = *(const bf16x8*)&qkv[(tok0 + i0 + wr + mi * 16 + lr) * QKVN
                                             + h * DHh + kk * 32 + kg];

    f32x4 o[2][2];
    #pragma unroll
    for (int mi = 0; mi < 2; ++mi)
        #pragma unroll
        for (int ni = 0; ni < 2; ++ni)
            o[mi][ni] = (f32x4){0.f, 0.f, 0.f, 0.f};

    if (tid < 64) { m_s[tid] = -3.0e38f; l_s[tid] = 0.f; }
    __syncthreads();

    for (int j0 = 0; j0 < Ss; j0 += 64) {
        #pragma unroll
        for (int i = 0; i < 2; ++i) {
            int ix = i * 256 + tid;
            int r = ix >> 3, c = (ix & 7) << 3;
            uint4 kq = *(const uint4*)&qkv[(tok0 + j0 + r) * QKVN + Hh + h * DHh + c];
            *(uint4*)&K_lds[(size_t)r * VS + c] = kq;
        }
        {
            int kv0 = (tid & 15) * 4;
            int d0 = (tid >> 4) * 4;
            uint2 rv[4];
            #pragma unroll
            for (int r = 0; r < 4; ++r)
                rv[r] = *(const uint2*)&qkv[(tok0 + j0 + kv0 + r) * QKVN
                                            + 2 * Hh + h * DHh + d0];
            #pragma unroll
            for (int c = 0; c < 4; ++c) {
                unsigned e0 = (c < 2) ? (rv[0].x >> (16 * c)) : (rv[0].y >> (16 * (c - 2)));
                unsigned e1 = (c < 2) ? (rv[1].x >> (16 * c)) : (rv[1].y >> (16 * (c - 2)));
                unsigned e2 = (c < 2) ? (rv[2].x >> (16 * c)) : (rv[2].y >> (16 * (c - 2)));
                unsigned e3 = (c < 2) ? (rv[3].x >> (16 * c)) : (rv[3].y >> (16 * (c - 2)));
                uint2 packed;
                packed.x = (e0 & 0xffffu) | (e1 << 16);
                packed.y = (e2 & 0xffffu) | (e3 << 16);
                *(uint2*)&Vt_lds[(size_t)(d0 + c) * VS + kv0] = packed;
            }
        }
        __syncthreads();

        f32x4 s[2][2];
        #pragma unroll
        for (int mi = 0; mi < 2; ++mi)
            #pragma unroll
            for (int ni = 0; ni < 2; ++ni)
                s[mi][ni] = (f32x4){0.f, 0.f, 0.f, 0.f};
        #pragma unroll
        for (int ni = 0; ni < 2; ++ni)
            #pragma unroll
            for (int kk = 0; kk < 2; ++kk) {
                bf16x8 kf = *(const bf16x8*)&K_lds[(size_t)(wc + ni * 16 + lr) * VS
                                                   + kk * 32 + kg];
                #pragma unroll
                for (int mi = 0; mi < 2; ++mi)
                    s[mi][ni] = __builtin_amdgcn_mfma_f32_16x16x32_bf16(
                        qf[mi][kk], kf, s[mi][ni], 0, 0, 0);
            }
        #pragma unroll
        for (int mi = 0; mi < 2; ++mi)
            #pragma unroll
            for (int ni = 0; ni < 2; ++ni)
                #pragma unroll
                for (int q = 0; q < 4; ++q) {
                    int rl = wr + mi * 16 + hi * 4 + q;
                    int cl = wc + ni * 16 + lr;
                    int gi = i0 + rl, gj = j0 + cl;
                    bool vis = (!has) || (gj <= sep) || ((gi > sep) && (gj <= gi));
                    S_lds[rl * SP + cl] = s[mi][ni][q] * 0.125f
                                          + (vis ? 0.0f : -1000000000.0f);
                }
        __syncthreads();

        {
            int r = tid >> 2, c0 = (tid & 3) * 16;
            float mold = m_s[r];
            float sv[16];
            float tmax = -3.0e38f;
            #pragma unroll
            for (int c = 0; c < 16; ++c) {
                sv[c] = S_lds[r * SP + c0 + c];
                tmax = fmaxf(tmax, sv[c]);
            }
            tmax = fmaxf(tmax, __shfl_xor(tmax, 1));
            tmax = fmaxf(tmax, __shfl_xor(tmax, 2));
            float mnew = fmaxf(mold, tmax);
            float sum = 0.f;
            #pragma unroll
            for (int c = 0; c < 16; ++c) {
                float p = __expf(sv[c] - mnew);
                P_lds[r * PS + c0 + c] = f2bf(p);
                sum += p;
            }
            sum += __shfl_xor(sum, 1);
            sum += __shfl_xor(sum, 2);
            if ((tid & 3) == 0) {
                float rf = __expf(mold - mnew);
                rf_s[r] = rf;
                l_s[r] = l_s[r] * rf + sum;
                m_s[r] = mnew;
            }
        }
        __syncthreads();

        #pragma unroll
        for (int mi = 0; mi < 2; ++mi)
            #pragma unroll
            for (int q = 0; q < 4; ++q) {
                float rf = rf_s[wr + mi * 16 + hi * 4 + q];
                #pragma unroll
                for (int ni = 0; ni < 2; ++ni)
                    o[mi][ni][q] *= rf;
            }
        #pragma unroll
        for (int kk = 0; kk < 2; ++kk) {
            bf16x8 pf[2];
            #pragma unroll
            for (int mi = 0; mi < 2; ++mi)
                pf[mi] = *(const bf16x8*)&P_lds[(size_t)(wr + mi * 16 + lr) * PS
                                                + kk * 32 + kg];
            #pragma unroll
            for (int ni = 0; ni < 2; ++ni) {
                bf16x8 vf = *(const bf16x8*)&Vt_lds[(size_t)(wc + ni * 16 + lr) * VS
                                                    + kk * 32 + kg];
                #pragma unroll
                for (int mi = 0; mi < 2; ++mi)
                    o[mi][ni] = __builtin_amdgcn_mfma_f32_16x16x32_bf16(
                        pf[mi], vf, o[mi][ni], 0, 0, 0);
            }
        }
        __syncthreads();
    }

    #pragma unroll
    for (int mi = 0; mi < 2; ++mi)
        #pragma unroll
        for (int q = 0; q < 4; ++q) {
            int rl = wr + mi * 16 + hi * 4 + q;
            float inv = 1.0f / l_s[rl];
            #pragma unroll
            for (int ni = 0; ni < 2; ++ni)
                ctx[(tok0 + i0 + rl) * Hh + h * DHh + wc + ni * 16 + lr]
                    = f2bf(o[mi][ni][q] * inv);
        }
}

// ---------------------------------------------------------------------------
// 7. Fused MFMA classifier, fixed-shift LSE. BK=64 + XOR swizzle.
// ---------------------------------------------------------------------------
__global__ __launch_bounds__(256) void cls_lse_kernel(
    const ushort* __restrict__ A,
    const ushort* __restrict__ WT,
    const float* __restrict__ cbp,
    const int* __restrict__ labels,
    float* __restrict__ psv, float* __restrict__ pll)
{
    __shared__ __align__(16) ushort As[128 * 64];
    __shared__ __align__(16) ushort Bs[128 * 64];
    __shared__ float ssum[2][128];
    __shared__ float sll[128];
    __shared__ int lab[128];
    const int tid = threadIdx.x;
    const int lane = tid & 63, wid = tid >> 6;
    const int m0 = blockIdx.y * 128;
    const int chunk = blockIdx.x;
    if (tid < 128) {
        sll[tid] = 0.f;
        lab[tid] = labels[m0 + tid];
    }
    const int wr = (wid >> 1) * 64, wcid = wid & 1, wc = wcid * 64;
    const int lr = lane & 15;
    const int hi = lane >> 4;

    float sacc[16];
    #pragma unroll
    for (int i = 0; i < 16; ++i) sacc[i] = 0.f;

    for (int t = 0; t < TPC; ++t) {
        const int n0 = (chunk * TPC + t) * 128;
        f32x4 acc[4][4];
        #pragma unroll
        for (int mi = 0; mi < 4; ++mi)
            #pragma unroll
            for (int ni = 0; ni < 4; ++ni)
                acc[mi][ni] = (f32x4){0.f, 0.f, 0.f, 0.f};

        for (int k0 = 0; k0 < Hh; k0 += 64) {
            #pragma unroll
            for (int i = 0; i < 4; ++i) {
                int idx = i * 256 + tid;
                int r = idx >> 3;
                int cs = ((idx & 7) ^ (r & 7)) << 3;
                __builtin_amdgcn_global_load_lds(
                    (const __attribute__((address_space(1))) void*)(A + (size_t)(m0 + r) * Hh + k0 + cs),
                    (__attribute__((address_space(3))) void*)(As + (size_t)(i * 256 + (wid << 6)) * 8),
                    16, 0, 0);
            }
            #pragma unroll
            for (int i = 0; i < 4; ++i) {
                int idx = i * 256 + tid;
                int r = idx >> 3;
                int cs = ((idx & 7) ^ (r & 7)) << 3;
                __builtin_amdgcn_global_load_lds(
                    (const __attribute__((address_space(1))) void*)(WT + (size_t)(n0 + r) * Hh + k0 + cs),
                    (__attribute__((address_space(3))) void*)(Bs + (size_t)(i * 256 + (wid << 6)) * 8),
                    16, 0, 0);
            }
            __syncthreads();

            #pragma unroll
            for (int kk = 0; kk < 2; ++kk) {
                bf16x8 af[4], bfr[4];
                #pragma unroll
                for (int mi = 0; mi < 4; ++mi) {
                    int row = wr + mi * 16 + lr;
                    int pc = ((kk << 2) + hi) ^ (row & 7);
                    af[mi] = *(const bf16x8*)(As + (size_t)row * 64 + (pc << 3));
                }
                #pragma unroll
                for (int ni = 0; ni < 4; ++ni) {
                    int row = wc + ni * 16 + lr;
                    int pc = ((kk << 2) + hi) ^ (row & 7);
                    bfr[ni] = *(const bf16x8*)(Bs + (size_t)row * 64 + (pc << 3));
                }
                #pragma unroll
                for (int mi = 0; mi < 4; ++mi)
                    #pragma unroll
                    for (int ni = 0; ni < 4; ++ni)
                        acc[mi][ni] = __builtin_amdgcn_mfma_f32_16x16x32_bf16(
                            af[mi], bfr[ni], acc[mi][ni], 0, 0, 0);
            }
            __syncthreads();
        }

        float bvs[4];
        int cols[4];
        #pragma unroll
        for (int ni = 0; ni < 4; ++ni) {
            cols[ni] = n0 + wc + ni * 16 + lr;
            bvs[ni] = cbp[cols[ni]];
        }
        #pragma unroll
        for (int mi = 0; mi < 4; ++mi) {
            #pragma unroll
            for (int q = 0; q < 4; ++q) {
                int rl = wr + mi * 16 + hi * 4 + q;
                float v0 = acc[mi][0][q] + bvs[0];
                float v1 = acc[mi][1][q] + bvs[1];
                float v2 = acc[mi][2][q] + bvs[2];
                float v3 = acc[mi][3][q] + bvs[3];
                int lb = lab[rl];
                if (lb == cols[0]) sll[rl] = v0;
                if (lb == cols[1]) sll[rl] = v1;
                if (lb == cols[2]) sll[rl] = v2;
                if (lb == cols[3]) sll[rl] = v3;
                sacc[mi * 4 + q] += __expf(v0 - LSE_SHIFT) + __expf(v1 - LSE_SHIFT)
                                  + __expf(v2 - LSE_SHIFT) + __expf(v3 - LSE_SHIFT);
            }
        }
    }

    #pragma unroll
    for (int mi = 0; mi < 4; ++mi) {
        #pragma unroll
        for (int q = 0; q < 4; ++q) {
            float s = sacc[mi * 4 + q];
            s += __shfl_xor(s, 1);
            s += __shfl_xor(s, 2);
            s += __shfl_xor(s, 4);
            s += __shfl_xor(s, 8);
            if (lr == 0) ssum[wcid][wr + mi * 16 + hi * 4 + q] = s;
        }
    }
    __syncthreads();
    if (tid < 128) {
        psv[(size_t)chunk * Mm + m0 + tid] = ssum[0][tid] + ssum[1][tid];
        pll[(size_t)chunk * Mm + m0 + tid] = sll[tid];
    }
}

// 7b. Merge chunk partials + masked per-sample mean (one block per batch)
__global__ __launch_bounds__(256) void cls_finish_kernel(
    const float* __restrict__ psv, const float* __restrict__ pll,
    const int* __restrict__ info, float* __restrict__ ps)
{
    int b = blockIdx.x, tid = threadIdx.x;
    int first = info[b * 4 + 0], has = info[b * 4 + 1];
    float sum = 0.f;
    #pragma unroll
    for (int rr = 0; rr < 2; ++rr) {
        int s = tid + rr * 256;
        int row = b * Ss + s;
        float sv = 0.f, l = 0.f;
        #pragma unroll 1
        for (int c = 0; c < NCH; ++c) {
            sv += psv[(size_t)c * Mm + row];
            l  += pll[(size_t)c * Mm + row];
        }
        float cev = (LSE_SHIFT + logf(sv)) - l;
        bool mv = has ? (s > first) : true;
        if (mv) sum += cev;
    }
    #pragma unroll
    for (int off = 32; off; off >>= 1) sum += __shfl_xor(sum, off);
    __shared__ float red[4];
    int lane = tid & 63, wid = tid >> 6;
    if (lane == 0) red[wid] = sum;
    __syncthreads();
    if (tid == 0) {
        float tot = red[0] + red[1] + red[2] + red[3];
        float cnt = has ? (float)(Ss - 1 - first) : (float)Ss;
        ps[b] = tot / cnt;
    }
}

__global__ void final_kernel(const float* __restrict__ ps, float* __restrict__ out)
{
    if (threadIdx.x == 0 && blockIdx.x == 0) {
        float t = 0.0f;
        #pragma unroll
        for (int b = 0; b < Bb; b++) t += ps[b];
        out[0] = t * (1.0f / Bb);
    }
}

// ---------------------------------------------------------------------------
// Host launcher
// ---------------------------------------------------------------------------
extern "C" void kernel_launch(void* const* d_in, const int* in_sizes, int n_in,
                              void* d_out, int out_size, void* d_ws, size_t ws_size,
                              hipStream_t stream)
{
    const int*   ids    = (const int*)d_in[0];
    const int*   labels = (const int*)d_in[1];
    const float* we     = (const float*)d_in[2];
    const float* pe     = (const float*)d_in[3];
    const float* te     = (const float*)d_in[4];
    const float* eg     = (const float*)d_in[5];
    const float* ebp    = (const float*)d_in[6];
    const float* Wq     = (const float*)d_in[7];
    const float* bq     = (const float*)d_in[8];
    const float* Wk     = (const float*)d_in[9];
    const float* bk     = (const float*)d_in[10];
    const float* Wv     = (const float*)d_in[11];
    const float* bv     = (const float*)d_in[12];
    const float* Wo     = (const float*)d_in[13];
    const float* bo     = (const float*)d_in[14];
    const float* l1g    = (const float*)d_in[15];
    const float* l1b    = (const float*)d_in[16];
    const float* W1     = (const float*)d_in[17];
    const float* b1     = (const float*)d_in[18];
    const float* W2     = (const float*)d_in[19];
    const float* b2     = (const float*)d_in[20];
    const float* l2g    = (const float*)d_in[21];
    const float* l2b    = (const float*)d_in[22];
    const float* cW     = (const float*)d_in[23];
    const float* cbias  = (const float*)d_in[24];

    const size_t MH  = (size_t)Mm * Hh;
    const size_t MF  = (size_t)Mm * Ff;
    const size_t HHe = (size_t)Hh * Hh;
    const size_t HFe = (size_t)Hh * Ff;

    // Workspace layout (~112 MB; proven >= 226.5 MB available)
    float* ws = (float*)d_ws;
    float* x      = ws;                                // MH f32
    float* ps     = x + MH;                            // 16 f32
    int*   info   = (int*)(ps + 16);                   // 64 ints reserved
    float* bqkv   = (float*)(info + 64);               // 2304 f32
    ushort* tmpb  = (ushort*)(bqkv + QKVN);            // 4*MH bf16 split-K partials
    ushort* xb    = tmpb + 4 * MH;                     // MH bf16
    ushort* qkvb  = xb + MH;                           // 3*MH bf16
    ushort* ctxb  = qkvb + 3 * MH;                     // MH
    ushort* f1b   = ctxb + MH;                         // MF
    ushort* wscr  = f1b + MF;                          // 4*HHe + 2*HFe bf16
    ushort* wqT = wscr;
    ushort* woT = wqT + 3 * HHe;                       // qkvoT[3] = Wo slot
    ushort* w1T = wscr + 4 * HHe;                      // [F][H]
    ushort* w2T = w1T + HFe;                           // [H][F]
    float* clsf = (float*)(w2T + HFe);
    float* cbp  = clsf;                                // VP
    float* psv  = cbp + VP;                            // NCH*Mm
    float* pll  = psv + (size_t)NCH * Mm;              // NCH*Mm
    ushort* cWT = qkvb;   // alias: qkvb..f1b dead at classifier time

    sep_kernel<<<Bb, 512, 0, stream>>>(ids, info);
    embed_ln_kernel<<<Mm, 256, 0, stream>>>(ids, we, pe, te, eg, ebp, x, xb);

    dim3 gQKV(QKVN / 128, Mm / 128);          // (18, 32)
    dim3 gWo(Hh / 128, Mm / 128, 4);          // (6, 32, 4) split-K (K=192/chunk)
    dim3 gF(Ff / 128, Mm / 128);              // (24, 32)
    dim3 gW2(Hh / 128, Mm / 128, 4);          // (6, 32, 4) split-K (K=768/chunk)
    dim3 gA(Ss / 64, Bb * NHh);               // (8, 96)

    for (int l = 0; l < Ll; l++) {
        const float* bo_l = bo + (size_t)l * Hh;
        const float* b1_l = b1 + (size_t)l * Ff;
        const float* b2_l = b2 + (size_t)l * Hh;
        const float* g1  = l1g + (size_t)l * Hh;
        const float* be1 = l1b + (size_t)l * Hh;
        const float* g2  = l2g + (size_t)l * Hh;
        const float* be2 = l2b + (size_t)l * Hh;

        prep_kernel<<<6913, 256, 0, stream>>>(
            Wq + (size_t)l * HHe, Wk + (size_t)l * HHe,
            Wv + (size_t)l * HHe, Wo + (size_t)l * HHe,
            W1 + (size_t)l * HFe, W2 + (size_t)l * HFe,
            bq + (size_t)l * Hh, bk + (size_t)l * Hh, bv + (size_t)l * Hh,
            wscr, w1T, w2T, bqkv);

        // Fused QKV projection: [M][768] @ [2304][768]^T -> [M][2304]
        mfma_gemm<0, 1, 1><<<gQKV, 256, 0, stream>>>(xb, wqT, bqkv, qkvb,
                                                     QKVN, Hh, Hh, Hh);

        flash_attn_kernel<<<gA, 256, 0, stream>>>(qkvb, info, ctxb);

        // Wo projection split-K x4: bf16 partials in tmpb, bias folded into LN
        mfma_gemm<0, 1, 0><<<gWo, 256, 0, stream>>>(ctxb, woT, nullptr, tmpb,
                                                    Hh, Hh / 4, Hh, Hh);
        resid_ln4_kernel<<<Mm, 256, 0, stream>>>(x, tmpb, bo_l, g1, be1, x, xb);

        mfma_gemm<1, 1, 1><<<gF, 256, 0, stream>>>(xb, w1T, b1_l, f1b,
                                                   Ff, Hh, Hh, Hh);
        // FFN2 split-K x4: bf16 partials in tmpb
        mfma_gemm<0, 1, 0><<<gW2, 256, 0, stream>>>(f1b, w2T, nullptr, tmpb,
                                                    Hh, Hh /*chunk*/, Ff, Ff);
        resid_ln4_kernel<<<Mm, 256, 0, stream>>>(x, tmpb, b2_l, g2, be2, x, xb);
    }

    // Classifier
    pad_transpose_kernel<<<dim3(VP / 32, Hh / 32), 256, 0, stream>>>(cW, cWT, Hh, Vv);
    bias_pad_kernel<<<(VP + 255) / 256, 256, 0, stream>>>(cbias, cbp);
    cls_lse_kernel<<<dim3(NCH, Mm / 128), 256, 0, stream>>>(
        xb, cWT, cbp, labels, psv, pll);
    cls_finish_kernel<<<Bb, 256, 0, stream>>>(psv, pll, info, ps);
    final_kernel<<<1, 64, 0, stream>>>(ps, (float*)d_out);
}

// Round 13
// 2495.510 us; speedup vs baseline: 1.1085x; 1.1085x over previous
//
#include <hip/hip_runtime.h>
#include <math.h>

typedef unsigned short ushort;
typedef __bf16 bf16x8 __attribute__((ext_vector_type(8)));
typedef float f32x4 __attribute__((ext_vector_type(4)));

// Problem dims
constexpr int Bb  = 8;
constexpr int Ss  = 512;
constexpr int Hh  = 768;
constexpr int Ll  = 12;
constexpr int NHh = 12;
constexpr int Ff  = 3072;
constexpr int Vv  = 21128;
constexpr int DHh = 64;
constexpr int Mm  = Bb * Ss;   // 4096
constexpr int SEP_ID = 102;
constexpr int VP  = 21504;     // vocab padded to 168*128
constexpr int NCH = 42;        // vocab chunks (cls grid x)
constexpr int TPC = 4;         // 128-col tiles per chunk
constexpr int QKVN = 3 * Hh;   // 2304
constexpr float LSE_SHIFT = 20.0f;

static __device__ __forceinline__ ushort f2bf(float f) {
    unsigned u = __float_as_uint(f);
    unsigned r = (u + 0x7fffu + ((u >> 16) & 1u)) >> 16;
    return (ushort)r;
}
static __device__ __forceinline__ float bf2f(unsigned x) {
    return __uint_as_float(x << 16);
}

// ---------------------------------------------------------------------------
// 1. Find first SEP per batch
// ---------------------------------------------------------------------------
__global__ __launch_bounds__(512) void sep_kernel(const int* __restrict__ ids,
                                                  int* __restrict__ info)
{
    int b = blockIdx.x;
    int t = threadIdx.x;
    int v = (ids[b * Ss + t] == SEP_ID) ? t : 0x7FFFFFFF;
    #pragma unroll
    for (int off = 32; off; off >>= 1) {
        int o = __shfl_xor(v, off);
        v = min(v, o);
    }
    __shared__ int wmin[8];
    int lane = t & 63, wid = t >> 6;
    if (lane == 0) wmin[wid] = v;
    __syncthreads();
    if (t == 0) {
        int first = wmin[0];
        #pragma unroll
        for (int w = 1; w < 8; w++) first = min(first, wmin[w]);
        int has = (first != 0x7FFFFFFF) ? 1 : 0;
        info[b * 4 + 0] = first;
        info[b * 4 + 1] = has;
        info[b * 4 + 2] = has ? min(first, Ss - 2) : (Ss + 1);
    }
}

// ---------------------------------------------------------------------------
// 2. Embedding + LayerNorm -> fp32 x and bf16 xb
// ---------------------------------------------------------------------------
__global__ __launch_bounds__(256) void embed_ln_kernel(
    const int* __restrict__ ids, const float* __restrict__ we,
    const float* __restrict__ pe, const float* __restrict__ te,
    const float* __restrict__ g, const float* __restrict__ bp,
    float* __restrict__ x, ushort* __restrict__ xb)
{
    int tok = blockIdx.x;
    int s = tok & (Ss - 1);
    int tid = threadIdx.x;
    int id = ids[tok];
    float e[3];
    #pragma unroll
    for (int r = 0; r < 3; r++) {
        int h = tid + (r << 8);
        e[r] = we[(size_t)id * Hh + h] + pe[(size_t)s * Hh + h] + te[h];
    }
    float sum = e[0] + e[1] + e[2];
    float sq  = fmaf(e[0], e[0], fmaf(e[1], e[1], e[2] * e[2]));
    #pragma unroll
    for (int off = 32; off; off >>= 1) {
        sum += __shfl_xor(sum, off);
        sq  += __shfl_xor(sq, off);
    }
    __shared__ float red[8];
    int lane = tid & 63, wid = tid >> 6;
    if (lane == 0) { red[wid] = sum; red[4 + wid] = sq; }
    __syncthreads();
    sum = red[0] + red[1] + red[2] + red[3];
    sq  = red[4] + red[5] + red[6] + red[7];
    float mean = sum * (1.0f / Hh);
    float var  = sq * (1.0f / Hh) - mean * mean;
    float rstd = rsqrtf(var + 1e-12f);
    #pragma unroll
    for (int r = 0; r < 3; r++) {
        int h = tid + (r << 8);
        float v = (e[r] - mean) * rstd * g[h] + bp[h];
        x[(size_t)tok * Hh + h] = v;
        xb[(size_t)tok * Hh + h] = f2bf(v);
    }
}

// ---------------------------------------------------------------------------
// 3. Residual + 4 split-K bf16 partials + bias + LayerNorm
// ---------------------------------------------------------------------------
__global__ __launch_bounds__(256) void resid_ln4_kernel(
    const float* __restrict__ resid, const ushort* __restrict__ p,  // [4][Mm][Hh] bf16
    const float* __restrict__ bias, const float* __restrict__ g,
    const float* __restrict__ bp,
    float* __restrict__ out, ushort* __restrict__ outb)
{
    const size_t MHl = (size_t)Mm * Hh;
    int tok = blockIdx.x;
    int tid = threadIdx.x;
    float e[3];
    #pragma unroll
    for (int r = 0; r < 3; r++) {
        int h = tid + (r << 8);
        size_t idx = (size_t)tok * Hh + h;
        float acc = resid[idx] + bias[h];
        acc += bf2f(p[idx]);
        acc += bf2f(p[MHl + idx]);
        acc += bf2f(p[2 * MHl + idx]);
        acc += bf2f(p[3 * MHl + idx]);
        e[r] = acc;
    }
    float sum = e[0] + e[1] + e[2];
    float sq  = fmaf(e[0], e[0], fmaf(e[1], e[1], e[2] * e[2]));
    #pragma unroll
    for (int off = 32; off; off >>= 1) {
        sum += __shfl_xor(sum, off);
        sq  += __shfl_xor(sq, off);
    }
    __shared__ float red[8];
    int lane = tid & 63, wid = tid >> 6;
    if (lane == 0) { red[wid] = sum; red[4 + wid] = sq; }
    __syncthreads();
    sum = red[0] + red[1] + red[2] + red[3];
    sq  = red[4] + red[5] + red[6] + red[7];
    float mean = sum * (1.0f / Hh);
    float var  = sq * (1.0f / Hh) - mean * mean;
    float rstd = rsqrtf(var + 1e-12f);
    #pragma unroll
    for (int r = 0; r < 3; r++) {
        int h = tid + (r << 8);
        float v = (e[r] - mean) * rstd * g[h] + bp[h];
        out[(size_t)tok * Hh + h] = v;
        outb[(size_t)tok * Hh + h] = f2bf(v);
    }
}

// ---------------------------------------------------------------------------
// 4. Fused per-layer weight prep: 4 HxH + HxF + FxH transposes + bias concat
// ---------------------------------------------------------------------------
__global__ __launch_bounds__(256) void prep_kernel(
    const float* __restrict__ Wq, const float* __restrict__ Wk,
    const float* __restrict__ Wv, const float* __restrict__ Wo,
    const float* __restrict__ W1, const float* __restrict__ W2,
    const float* __restrict__ bq, const float* __restrict__ bk,
    const float* __restrict__ bv,
    ushort* __restrict__ qkvoT, ushort* __restrict__ w1T,
    ushort* __restrict__ w2T, float* __restrict__ bqkv)
{
    int b = blockIdx.x;
    if (b >= 6912) {   // bias concat
        for (int j = threadIdx.x; j < Hh; j += 256) {
            bqkv[j]          = bq[j];
            bqkv[Hh + j]     = bk[j];
            bqkv[2 * Hh + j] = bv[j];
        }
        return;
    }
    const float* W;
    ushort* Wt;
    int K, N, n0, k0;
    if (b < 2304) {          // QKVO: 4 x 576 tiles of HxH
        int which = b / 576, t = b % 576;
        const float* srcs[4] = { Wq, Wk, Wv, Wo };
        W = srcs[which];
        Wt = qkvoT + (size_t)which * Hh * Hh;
        K = Hh; N = Hh;
        n0 = (t % 24) * 32; k0 = (t / 24) * 32;
    } else if (b < 4608) {   // W1: [Hh][Ff] -> w1T [Ff][Hh]
        int t = b - 2304;
        W = W1; Wt = w1T; K = Hh; N = Ff;
        n0 = (t % 96) * 32; k0 = (t / 96) * 32;
    } else {                 // W2: [Ff][Hh] -> w2T [Hh][Ff]
        int t = b - 4608;
        W = W2; Wt = w2T; K = Ff; N = Hh;
        n0 = (t % 24) * 32; k0 = (t / 24) * 32;
    }
    __shared__ float ts[32][33];
    int tx = threadIdx.x & 31, ty = threadIdx.x >> 5;
    #pragma unroll
    for (int i = 0; i < 32; i += 8)
        ts[ty + i][tx] = W[(size_t)(k0 + ty + i) * N + n0 + tx];
    __syncthreads();
    #pragma unroll
    for (int i = 0; i < 32; i += 8)
        Wt[(size_t)(n0 + ty + i) * K + k0 + tx] = f2bf(ts[tx][ty + i]);
}

// 4b. Padded transpose + bias pad for classifier
__global__ __launch_bounds__(256) void pad_transpose_kernel(
    const float* __restrict__ W, ushort* __restrict__ Wt, int K, int N)
{
    __shared__ float ts[32][33];
    int n0 = blockIdx.x * 32, k0 = blockIdx.y * 32;
    int tx = threadIdx.x & 31, ty = threadIdx.x >> 5;
    #pragma unroll
    for (int i = 0; i < 32; i += 8) {
        int n = n0 + tx;
        ts[ty + i][tx] = (n < N) ? W[(size_t)(k0 + ty + i) * N + n] : 0.f;
    }
    __syncthreads();
    #pragma unroll
    for (int i = 0; i < 32; i += 8)
        Wt[(size_t)(n0 + ty + i) * K + k0 + tx] = f2bf(ts[tx][ty + i]);
}

__global__ __launch_bounds__(256) void bias_pad_kernel(
    const float* __restrict__ cb, float* __restrict__ cbp)
{
    int i = blockIdx.x * 256 + threadIdx.x;
    if (i < VP) cbp[i] = (i < Vv) ? cb[i] : -1.0e9f;
}

// ---------------------------------------------------------------------------
// 5. bf16 MFMA GEMM (m97-pattern, BK=32), split-K via gridDim.z.
//    OUT_BF=1 writes bf16 (z-offset partials when gridDim.z>1);
//    OUT_BF=0 writes f32 with z-offset.
// ---------------------------------------------------------------------------
template <int ACT, int OUT_BF, int BIAS>
__global__ __launch_bounds__(256) void mfma_gemm(
    const ushort* __restrict__ A,
    const ushort* __restrict__ Bt,
    const float* __restrict__ bias,
    void* __restrict__ C,
    int N, int K, int lda, int ldb)
{
    __shared__ __align__(16) ushort As[128 * 32];
    __shared__ __align__(16) ushort Bs[128 * 32];
    const int tid = threadIdx.x;
    const int lane = tid & 63, wid = tid >> 6;
    const int m0 = blockIdx.y * 128, n0 = blockIdx.x * 128;
    const int kbase = blockIdx.z * K;
    const size_t zoff = (size_t)blockIdx.z * Mm * N;
    A += kbase;
    Bt += kbase;
    const int wr = (wid >> 1) * 64, wc = (wid & 1) * 64;
    const int lr = lane & 15;
    const int kg = (lane >> 4) << 3;

    f32x4 acc[4][4];
    #pragma unroll
    for (int mi = 0; mi < 4; ++mi)
        #pragma unroll
        for (int ni = 0; ni < 4; ++ni)
            acc[mi][ni] = (f32x4){0.f, 0.f, 0.f, 0.f};

    for (int k0 = 0; k0 < K; k0 += 32) {
        #pragma unroll
        for (int i = 0; i < 2; ++i) {
            int idx = i * 256 + tid;
            int r = idx >> 2, c = (idx & 3) << 3;
            __builtin_amdgcn_global_load_lds(
                (const __attribute__((address_space(1))) void*)(A + (size_t)(m0 + r) * lda + k0 + c),
                (__attribute__((address_space(3))) void*)(As + (size_t)(i * 256 + (wid << 6)) * 8),
                16, 0, 0);
        }
        #pragma unroll
        for (int i = 0; i < 2; ++i) {
            int idx = i * 256 + tid;
            int r = idx >> 2, c = (idx & 3) << 3;
            __builtin_amdgcn_global_load_lds(
                (const __attribute__((address_space(1))) void*)(Bt + (size_t)(n0 + r) * ldb + k0 + c),
                (__attribute__((address_space(3))) void*)(Bs + (size_t)(i * 256 + (wid << 6)) * 8),
                16, 0, 0);
        }
        __syncthreads();

        bf16x8 af[4], bfr[4];
        #pragma unroll
        for (int mi = 0; mi < 4; ++mi)
            af[mi] = *(const bf16x8*)(As + (size_t)(wr + mi * 16 + lr) * 32 + kg);
        #pragma unroll
        for (int ni = 0; ni < 4; ++ni)
            bfr[ni] = *(const bf16x8*)(Bs + (size_t)(wc + ni * 16 + lr) * 32 + kg);

        #pragma unroll
        for (int mi = 0; mi < 4; ++mi)
            #pragma unroll
            for (int ni = 0; ni < 4; ++ni)
                acc[mi][ni] = __builtin_amdgcn_mfma_f32_16x16x32_bf16(
                    af[mi], bfr[ni], acc[mi][ni], 0, 0, 0);
        __syncthreads();
    }

    #pragma unroll
    for (int ni = 0; ni < 4; ++ni) {
        int col = n0 + wc + ni * 16 + lr;
        float bsv = 0.f;
        if (BIAS) bsv = bias[col];
        #pragma unroll
        for (int mi = 0; mi < 4; ++mi) {
            f32x4 v = acc[mi][ni];
            #pragma unroll
            for (int q = 0; q < 4; ++q) {
                int row = m0 + wr + mi * 16 + ((lane >> 4) << 2) + q;
                float val = v[q] + bsv;
                if (ACT == 1) {
                    float y = 0.7978845608028654f
                              * (val + 0.044715f * val * val * val);
                    val = val / (1.0f + __expf(-2.0f * y));
                }
                if (OUT_BF)
                    ((ushort*)C)[zoff + (size_t)row * N + col] = f2bf(val);
                else
                    ((float*)C)[zoff + (size_t)row * N + col] = val;
            }
        }
    }
}

// ---------------------------------------------------------------------------
// 6. Fused MFMA flash attention (stride-72 conflict-free LDS)
// ---------------------------------------------------------------------------
constexpr int SP = 65;   // S_lds stride (f32)
constexpr int PS = 72;   // P_lds stride (u16)
constexpr int VS = 72;   // Vt_lds / K_lds stride (u16)

__global__ __launch_bounds__(256) void flash_attn_kernel(
    const ushort* __restrict__ qkv, const int* __restrict__ info,
    ushort* __restrict__ ctx)
{
    __shared__ __align__(16) ushort K_lds[64 * VS];
    __shared__ __align__(16) ushort Vt_lds[64 * VS];
    __shared__ __align__(16) ushort P_lds[64 * PS];
    __shared__ float S_lds[64 * SP];
    __shared__ float m_s[64], l_s[64], rf_s[64];

    const int tid = threadIdx.x;
    const int lane = tid & 63, wid = tid >> 6;
    const int bh = blockIdx.y, b = bh / NHh, h = bh % NHh;
    const int i0 = blockIdx.x * 64;
    const int lr = lane & 15, hi = lane >> 4;
    const int kg = hi << 3;
    const int wr = (wid >> 1) * 32;
    const int wc = (wid & 1) * 32;
    const int has = info[b * 4 + 1], sep = info[b * 4 + 2];
    const size_t tok0 = (size_t)b * Ss;

    bf16x8 qf[2][2];
    #pragma unroll
    for (int mi = 0; mi < 2; ++mi)
        #pragma unroll
        for (int kk = 0; kk < 2; ++kk)
            qf[mi][kk] = *(const bf16x8*)&qkv[(tok0 + i0 + wr + mi * 16 + lr) * QKVN
                                             + h * DHh + kk * 32 + kg];

    f32x4 o[2][2];
    #pragma unroll
    for (int mi = 0; mi < 2; ++mi)
        #pragma unroll
        for (int ni = 0; ni < 2; ++ni)
            o[mi][ni] = (f32x4){0.f, 0.f, 0.f, 0.f};

    if (tid < 64) { m_s[tid] = -3.0e38f; l_s[tid] = 0.f; }
    __syncthreads();

    for (int j0 = 0; j0 < Ss; j0 += 64) {
        #pragma unroll
        for (int i = 0; i < 2; ++i) {
            int ix = i * 256 + tid;
            int r = ix >> 3, c = (ix & 7) << 3;
            uint4 kq = *(const uint4*)&qkv[(tok0 + j0 + r) * QKVN + Hh + h * DHh + c];
            *(uint4*)&K_lds[(size_t)r * VS + c] = kq;
        }
        {
            int kv0 = (tid & 15) * 4;
            int d0 = (tid >> 4) * 4;
            uint2 rv[4];
            #pragma unroll
            for (int r = 0; r < 4; ++r)
                rv[r] = *(const uint2*)&qkv[(tok0 + j0 + kv0 + r) * QKVN
                                            + 2 * Hh + h * DHh + d0];
            #pragma unroll
            for (int c = 0; c < 4; ++c) {
                unsigned e0 = (c < 2) ? (rv[0].x >> (16 * c)) : (rv[0].y >> (16 * (c - 2)));
                unsigned e1 = (c < 2) ? (rv[1].x >> (16 * c)) : (rv[1].y >> (16 * (c - 2)));
                unsigned e2 = (c < 2) ? (rv[2].x >> (16 * c)) : (rv[2].y >> (16 * (c - 2)));
                unsigned e3 = (c < 2) ? (rv[3].x >> (16 * c)) : (rv[3].y >> (16 * (c - 2)));
                uint2 packed;
                packed.x = (e0 & 0xffffu) | (e1 << 16);
                packed.y = (e2 & 0xffffu) | (e3 << 16);
                *(uint2*)&Vt_lds[(size_t)(d0 + c) * VS + kv0] = packed;
            }
        }
        __syncthreads();

        f32x4 s[2][2];
        #pragma unroll
        for (int mi = 0; mi < 2; ++mi)
            #pragma unroll
            for (int ni = 0; ni < 2; ++ni)
                s[mi][ni] = (f32x4){0.f, 0.f, 0.f, 0.f};
        #pragma unroll
        for (int ni = 0; ni < 2; ++ni)
            #pragma unroll
            for (int kk = 0; kk < 2; ++kk) {
                bf16x8 kf = *(const bf16x8*)&K_lds[(size_t)(wc + ni * 16 + lr) * VS
                                                   + kk * 32 + kg];
                #pragma unroll
                for (int mi = 0; mi < 2; ++mi)
                    s[mi][ni] = __builtin_amdgcn_mfma_f32_16x16x32_bf16(
                        qf[mi][kk], kf, s[mi][ni], 0, 0, 0);
            }
        #pragma unroll
        for (int mi = 0; mi < 2; ++mi)
            #pragma unroll
            for (int ni = 0; ni < 2; ++ni)
                #pragma unroll
                for (int q = 0; q < 4; ++q) {
                    int rl = wr + mi * 16 + hi * 4 + q;
                    int cl = wc + ni * 16 + lr;
                    int gi = i0 + rl, gj = j0 + cl;
                    bool vis = (!has) || (gj <= sep) || ((gi > sep) && (gj <= gi));
                    S_lds[rl * SP + cl] = s[mi][ni][q] * 0.125f
                                          + (vis ? 0.0f : -1000000000.0f);
                }
        __syncthreads();

        {
            int r = tid >> 2, c0 = (tid & 3) * 16;
            float mold = m_s[r];
            float sv[16];
            float tmax = -3.0e38f;
            #pragma unroll
            for (int c = 0; c < 16; ++c) {
                sv[c] = S_lds[r * SP + c0 + c];
                tmax = fmaxf(tmax, sv[c]);
            }
            tmax = fmaxf(tmax, __shfl_xor(tmax, 1));
            tmax = fmaxf(tmax, __shfl_xor(tmax, 2));
            float mnew = fmaxf(mold, tmax);
            float sum = 0.f;
            #pragma unroll
            for (int c = 0; c < 16; ++c) {
                float p = __expf(sv[c] - mnew);
                P_lds[r * PS + c0 + c] = f2bf(p);
                sum += p;
            }
            sum += __shfl_xor(sum, 1);
            sum += __shfl_xor(sum, 2);
            if ((tid & 3) == 0) {
                float rf = __expf(mold - mnew);
                rf_s[r] = rf;
                l_s[r] = l_s[r] * rf + sum;
                m_s[r] = mnew;
            }
        }
        __syncthreads();

        #pragma unroll
        for (int mi = 0; mi < 2; ++mi)
            #pragma unroll
            for (int q = 0; q < 4; ++q) {
                float rf = rf_s[wr + mi * 16 + hi * 4 + q];
                #pragma unroll
                for (int ni = 0; ni < 2; ++ni)
                    o[mi][ni][q] *= rf;
            }
        #pragma unroll
        for (int kk = 0; kk < 2; ++kk) {
            bf16x8 pf[2];
            #pragma unroll
            for (int mi = 0; mi < 2; ++mi)
                pf[mi] = *(const bf16x8*)&P_lds[(size_t)(wr + mi * 16 + lr) * PS
                                                + kk * 32 + kg];
            #pragma unroll
            for (int ni = 0; ni < 2; ++ni) {
                bf16x8 vf = *(const bf16x8*)&Vt_lds[(size_t)(wc + ni * 16 + lr) * VS
                                                    + kk * 32 + kg];
                #pragma unroll
                for (int mi = 0; mi < 2; ++mi)
                    o[mi][ni] = __builtin_amdgcn_mfma_f32_16x16x32_bf16(
                        pf[mi], vf, o[mi][ni], 0, 0, 0);
            }
        }
        __syncthreads();
    }

    #pragma unroll
    for (int mi = 0; mi < 2; ++mi)
        #pragma unroll
        for (int q = 0; q < 4; ++q) {
            int rl = wr + mi * 16 + hi * 4 + q;
            float inv = 1.0f / l_s[rl];
            #pragma unroll
            for (int ni = 0; ni < 2; ++ni)
                ctx[(tok0 + i0 + rl) * Hh + h * DHh + wc + ni * 16 + lr]
                    = f2bf(o[mi][ni][q] * inv);
        }
}

// ---------------------------------------------------------------------------
// 7. Fused MFMA classifier, fixed-shift LSE. Grid (NCH=42, 32). BK=32.
// ---------------------------------------------------------------------------
__global__ __launch_bounds__(256) void cls_lse_kernel(
    const ushort* __restrict__ A,
    const ushort* __restrict__ WT,
    const float* __restrict__ cbp,
    const int* __restrict__ labels,
    float* __restrict__ psv, float* __restrict__ pll)
{
    __shared__ __align__(16) ushort As[128 * 32];
    __shared__ __align__(16) ushort Bs[128 * 32];
    __shared__ float ssum[2][128];
    __shared__ float sll[128];
    __shared__ int lab[128];
    const int tid = threadIdx.x;
    const int lane = tid & 63, wid = tid >> 6;
    const int m0 = blockIdx.y * 128;
    const int chunk = blockIdx.x;
    if (tid < 128) {
        sll[tid] = 0.f;
        lab[tid] = labels[m0 + tid];
    }
    const int wr = (wid >> 1) * 64, wcid = wid & 1, wc = wcid * 64;
    const int lr = lane & 15;
    const int hi = lane >> 4;
    const int kg = hi << 3;

    float sacc[16];
    #pragma unroll
    for (int i = 0; i < 16; ++i) sacc[i] = 0.f;

    for (int t = 0; t < TPC; ++t) {
        const int n0 = (chunk * TPC + t) * 128;
        f32x4 acc[4][4];
        #pragma unroll
        for (int mi = 0; mi < 4; ++mi)
            #pragma unroll
            for (int ni = 0; ni < 4; ++ni)
                acc[mi][ni] = (f32x4){0.f, 0.f, 0.f, 0.f};

        for (int k0 = 0; k0 < Hh; k0 += 32) {
            #pragma unroll
            for (int i = 0; i < 2; ++i) {
                int idx = i * 256 + tid;
                int r = idx >> 2, c = (idx & 3) << 3;
                __builtin_amdgcn_global_load_lds(
                    (const __attribute__((address_space(1))) void*)(A + (size_t)(m0 + r) * Hh + k0 + c),
                    (__attribute__((address_space(3))) void*)(As + (size_t)(i * 256 + (wid << 6)) * 8),
                    16, 0, 0);
            }
            #pragma unroll
            for (int i = 0; i < 2; ++i) {
                int idx = i * 256 + tid;
                int r = idx >> 2, c = (idx & 3) << 3;
                __builtin_amdgcn_global_load_lds(
                    (const __attribute__((address_space(1))) void*)(WT + (size_t)(n0 + r) * Hh + k0 + c),
                    (__attribute__((address_space(3))) void*)(Bs + (size_t)(i * 256 + (wid << 6)) * 8),
                    16, 0, 0);
            }
            __syncthreads();

            bf16x8 af[4], bfr[4];
            #pragma unroll
            for (int mi = 0; mi < 4; ++mi)
                af[mi] = *(const bf16x8*)(As + (size_t)(wr + mi * 16 + lr) * 32 + kg);
            #pragma unroll
            for (int ni = 0; ni < 4; ++ni)
                bfr[ni] = *(const bf16x8*)(Bs + (size_t)(wc + ni * 16 + lr) * 32 + kg);

            #pragma unroll
            for (int mi = 0; mi < 4; ++mi)
                #pragma unroll
                for (int ni = 0; ni < 4; ++ni)
                    acc[mi][ni] = __builtin_amdgcn_mfma_f32_16x16x32_bf16(
                        af[mi], bfr[ni], acc[mi][ni], 0, 0, 0);
            __syncthreads();
        }

        float bvs[4];
        int cols[4];
        #pragma unroll
        for (int ni = 0; ni < 4; ++ni) {
            cols[ni] = n0 + wc + ni * 16 + lr;
            bvs[ni] = cbp[cols[ni]];
        }
        #pragma unroll
        for (int mi = 0; mi < 4; ++mi) {
            #pragma unroll
            for (int q = 0; q < 4; ++q) {
                int rl = wr + mi * 16 + hi * 4 + q;
                float v0 = acc[mi][0][q] + bvs[0];
                float v1 = acc[mi][1][q] + bvs[1];
                float v2 = acc[mi][2][q] + bvs[2];
                float v3 = acc[mi][3][q] + bvs[3];
                int lb = lab[rl];
                if (lb == cols[0]) sll[rl] = v0;
                if (lb == cols[1]) sll[rl] = v1;
                if (lb == cols[2]) sll[rl] = v2;
                if (lb == cols[3]) sll[rl] = v3;
                sacc[mi * 4 + q] += __expf(v0 - LSE_SHIFT) + __expf(v1 - LSE_SHIFT)
                                  + __expf(v2 - LSE_SHIFT) + __expf(v3 - LSE_SHIFT);
            }
        }
    }

    #pragma unroll
    for (int mi = 0; mi < 4; ++mi) {
        #pragma unroll
        for (int q = 0; q < 4; ++q) {
            float s = sacc[mi * 4 + q];
            s += __shfl_xor(s, 1);
            s += __shfl_xor(s, 2);
            s += __shfl_xor(s, 4);
            s += __shfl_xor(s, 8);
            if (lr == 0) ssum[wcid][wr + mi * 16 + hi * 4 + q] = s;
        }
    }
    __syncthreads();
    if (tid < 128) {
        psv[(size_t)chunk * Mm + m0 + tid] = ssum[0][tid] + ssum[1][tid];
        pll[(size_t)chunk * Mm + m0 + tid] = sll[tid];
    }
}

// 7b. Merge chunk partials + masked per-sample mean (one block per batch)
__global__ __launch_bounds__(256) void cls_finish_kernel(
    const float* __restrict__ psv, const float* __restrict__ pll,
    const int* __restrict__ info, float* __restrict__ ps)
{
    int b = blockIdx.x, tid = threadIdx.x;
    int first = info[b * 4 + 0], has = info[b * 4 + 1];
    float sum = 0.f;
    #pragma unroll
    for (int rr = 0; rr < 2; ++rr) {
        int s = tid + rr * 256;
        int row = b * Ss + s;
        float sv = 0.f, l = 0.f;
        #pragma unroll 1
        for (int c = 0; c < NCH; ++c) {
            sv += psv[(size_t)c * Mm + row];
            l  += pll[(size_t)c * Mm + row];
        }
        float cev = (LSE_SHIFT + logf(sv)) - l;
        bool mv = has ? (s > first) : true;
        if (mv) sum += cev;
    }
    #pragma unroll
    for (int off = 32; off; off >>= 1) sum += __shfl_xor(sum, off);
    __shared__ float red[4];
    int lane = tid & 63, wid = tid >> 6;
    if (lane == 0) red[wid] = sum;
    __syncthreads();
    if (tid == 0) {
        float tot = red[0] + red[1] + red[2] + red[3];
        float cnt = has ? (float)(Ss - 1 - first) : (float)Ss;
        ps[b] = tot / cnt;
    }
}

__global__ void final_kernel(const float* __restrict__ ps, float* __restrict__ out)
{
    if (threadIdx.x == 0 && blockIdx.x == 0) {
        float t = 0.0f;
        #pragma unroll
        for (int b = 0; b < Bb; b++) t += ps[b];
        out[0] = t * (1.0f / Bb);
    }
}

// ---------------------------------------------------------------------------
// Host launcher
// ---------------------------------------------------------------------------
extern "C" void kernel_launch(void* const* d_in, const int* in_sizes, int n_in,
                              void* d_out, int out_size, void* d_ws, size_t ws_size,
                              hipStream_t stream)
{
    const int*   ids    = (const int*)d_in[0];
    const int*   labels = (const int*)d_in[1];
    const float* we     = (const float*)d_in[2];
    const float* pe     = (const float*)d_in[3];
    const float* te     = (const float*)d_in[4];
    const float* eg     = (const float*)d_in[5];
    const float* ebp    = (const float*)d_in[6];
    const float* Wq     = (const float*)d_in[7];
    const float* bq     = (const float*)d_in[8];
    const float* Wk     = (const float*)d_in[9];
    const float* bk     = (const float*)d_in[10];
    const float* Wv     = (const float*)d_in[11];
    const float* bv     = (const float*)d_in[12];
    const float* Wo     = (const float*)d_in[13];
    const float* bo     = (const float*)d_in[14];
    const float* l1g    = (const float*)d_in[15];
    const float* l1b    = (const float*)d_in[16];
    const float* W1     = (const float*)d_in[17];
    const float* b1     = (const float*)d_in[18];
    const float* W2     = (const float*)d_in[19];
    const float* b2     = (const float*)d_in[20];
    const float* l2g    = (const float*)d_in[21];
    const float* l2b    = (const float*)d_in[22];
    const float* cW     = (const float*)d_in[23];
    const float* cbias  = (const float*)d_in[24];

    const size_t MH  = (size_t)Mm * Hh;
    const size_t MF  = (size_t)Mm * Ff;
    const size_t HHe = (size_t)Hh * Hh;
    const size_t HFe = (size_t)Hh * Ff;

    // Workspace layout (~112 MB; proven >= 226.5 MB available)
    float* ws = (float*)d_ws;
    float* x      = ws;                                // MH f32
    float* ps     = x + MH;                            // 16 f32
    int*   info   = (int*)(ps + 16);                   // 64 ints reserved
    float* bqkv   = (float*)(info + 64);               // 2304 f32
    ushort* tmpb  = (ushort*)(bqkv + QKVN);            // 4*MH bf16 split-K partials
    ushort* xb    = tmpb + 4 * MH;                     // MH bf16
    ushort* qkvb  = xb + MH;                           // 3*MH bf16
    ushort* ctxb  = qkvb + 3 * MH;                     // MH
    ushort* f1b   = ctxb + MH;                         // MF
    ushort* wscr  = f1b + MF;                          // 4*HHe + 2*HFe bf16
    ushort* wqT = wscr;
    ushort* woT = wqT + 3 * HHe;                       // qkvoT[3] = Wo slot
    ushort* w1T = wscr + 4 * HHe;                      // [F][H]
    ushort* w2T = w1T + HFe;                           // [H][F]
    float* clsf = (float*)(w2T + HFe);
    float* cbp  = clsf;                                // VP
    float* psv  = cbp + VP;                            // NCH*Mm
    float* pll  = psv + (size_t)NCH * Mm;              // NCH*Mm
    ushort* cWT = qkvb;   // alias: qkvb..f1b dead at classifier time

    sep_kernel<<<Bb, 512, 0, stream>>>(ids, info);
    embed_ln_kernel<<<Mm, 256, 0, stream>>>(ids, we, pe, te, eg, ebp, x, xb);

    dim3 gQKV(QKVN / 128, Mm / 128);          // (18, 32)
    dim3 gWo(Hh / 128, Mm / 128, 4);          // (6, 32, 4) split-K (K=192/chunk)
    dim3 gF(Ff / 128, Mm / 128);              // (24, 32)
    dim3 gW2(Hh / 128, Mm / 128, 4);          // (6, 32, 4) split-K (K=768/chunk)
    dim3 gA(Ss / 64, Bb * NHh);               // (8, 96)

    for (int l = 0; l < Ll; l++) {
        const float* bo_l = bo + (size_t)l * Hh;
        const float* b1_l = b1 + (size_t)l * Ff;
        const float* b2_l = b2 + (size_t)l * Hh;
        const float* g1  = l1g + (size_t)l * Hh;
        const float* be1 = l1b + (size_t)l * Hh;
        const float* g2  = l2g + (size_t)l * Hh;
        const float* be2 = l2b + (size_t)l * Hh;

        prep_kernel<<<6913, 256, 0, stream>>>(
            Wq + (size_t)l * HHe, Wk + (size_t)l * HHe,
            Wv + (size_t)l * HHe, Wo + (size_t)l * HHe,
            W1 + (size_t)l * HFe, W2 + (size_t)l * HFe,
            bq + (size_t)l * Hh, bk + (size_t)l * Hh, bv + (size_t)l * Hh,
            wscr, w1T, w2T, bqkv);

        // Fused QKV projection: [M][768] @ [2304][768]^T -> [M][2304]
        mfma_gemm<0, 1, 1><<<gQKV, 256, 0, stream>>>(xb, wqT, bqkv, qkvb,
                                                     QKVN, Hh, Hh, Hh);

        flash_attn_kernel<<<gA, 256, 0, stream>>>(qkvb, info, ctxb);

        // Wo projection split-K x4: bf16 partials in tmpb, bias folded into LN
        mfma_gemm<0, 1, 0><<<gWo, 256, 0, stream>>>(ctxb, woT, nullptr, tmpb,
                                                    Hh, Hh / 4, Hh, Hh);
        resid_ln4_kernel<<<Mm, 256, 0, stream>>>(x, tmpb, bo_l, g1, be1, x, xb);

        mfma_gemm<1, 1, 1><<<gF, 256, 0, stream>>>(xb, w1T, b1_l, f1b,
                                                   Ff, Hh, Hh, Hh);
        // FFN2 split-K x4: bf16 partials in tmpb
        mfma_gemm<0, 1, 0><<<gW2, 256, 0, stream>>>(f1b, w2T, nullptr, tmpb,
                                                    Hh, Hh /*chunk*/, Ff, Ff);
        resid_ln4_kernel<<<Mm, 256, 0, stream>>>(x, tmpb, b2_l, g2, be2, x, xb);
    }

    // Classifier
    pad_transpose_kernel<<<dim3(VP / 32, Hh / 32), 256, 0, stream>>>(cW, cWT, Hh, Vv);
    bias_pad_kernel<<<(VP + 255) / 256, 256, 0, stream>>>(cbias, cbp);
    cls_lse_kernel<<<dim3(NCH, Mm / 128), 256, 0, stream>>>(
        xb, cWT, cbp, labels, psv, pll);
    cls_finish_kernel<<<Bb, 256, 0, stream>>>(psv, pll, info, ps);
    final_kernel<<<1, 64, 0, stream>>>(ps, (float*)d_out);
}

// Round 14
// 2489.161 us; speedup vs baseline: 1.1114x; 1.0026x over previous
//
#include <hip/hip_runtime.h>
#include <math.h>

typedef unsigned short ushort;
typedef __bf16 bf16x8 __attribute__((ext_vector_type(8)));
typedef float f32x4 __attribute__((ext_vector_type(4)));

// Problem dims
constexpr int Bb  = 8;
constexpr int Ss  = 512;
constexpr int Hh  = 768;
constexpr int Ll  = 12;
constexpr int NHh = 12;
constexpr int Ff  = 3072;
constexpr int Vv  = 21128;
constexpr int DHh = 64;
constexpr int Mm  = Bb * Ss;   // 4096
constexpr int SEP_ID = 102;
constexpr int VP  = 21504;     // vocab padded to 168*128
constexpr int NCH = 42;        // vocab chunks (cls grid x)
constexpr int TPC = 4;         // 128-col tiles per chunk
constexpr int QKVN = 3 * Hh;   // 2304
constexpr float LSE_SHIFT = 20.0f;

static __device__ __forceinline__ ushort f2bf(float f) {
    unsigned u = __float_as_uint(f);
    unsigned r = (u + 0x7fffu + ((u >> 16) & 1u)) >> 16;
    return (ushort)r;
}
static __device__ __forceinline__ float bf2f(unsigned x) {
    return __uint_as_float(x << 16);
}

// ---------------------------------------------------------------------------
// 1. Find first SEP per batch
// ---------------------------------------------------------------------------
__global__ __launch_bounds__(512) void sep_kernel(const int* __restrict__ ids,
                                                  int* __restrict__ info)
{
    int b = blockIdx.x;
    int t = threadIdx.x;
    int v = (ids[b * Ss + t] == SEP_ID) ? t : 0x7FFFFFFF;
    #pragma unroll
    for (int off = 32; off; off >>= 1) {
        int o = __shfl_xor(v, off);
        v = min(v, o);
    }
    __shared__ int wmin[8];
    int lane = t & 63, wid = t >> 6;
    if (lane == 0) wmin[wid] = v;
    __syncthreads();
    if (t == 0) {
        int first = wmin[0];
        #pragma unroll
        for (int w = 1; w < 8; w++) first = min(first, wmin[w]);
        int has = (first != 0x7FFFFFFF) ? 1 : 0;
        info[b * 4 + 0] = first;
        info[b * 4 + 1] = has;
        info[b * 4 + 2] = has ? min(first, Ss - 2) : (Ss + 1);
    }
}

// ---------------------------------------------------------------------------
// 2. Embedding + LayerNorm -> bf16 xb (residual carried in bf16, r14)
// ---------------------------------------------------------------------------
__global__ __launch_bounds__(256) void embed_ln_kernel(
    const int* __restrict__ ids, const float* __restrict__ we,
    const float* __restrict__ pe, const float* __restrict__ te,
    const float* __restrict__ g, const float* __restrict__ bp,
    ushort* __restrict__ xb)
{
    int tok = blockIdx.x;
    int s = tok & (Ss - 1);
    int tid = threadIdx.x;
    int id = ids[tok];
    float e[3];
    #pragma unroll
    for (int r = 0; r < 3; r++) {
        int h = tid + (r << 8);
        e[r] = we[(size_t)id * Hh + h] + pe[(size_t)s * Hh + h] + te[h];
    }
    float sum = e[0] + e[1] + e[2];
    float sq  = fmaf(e[0], e[0], fmaf(e[1], e[1], e[2] * e[2]));
    #pragma unroll
    for (int off = 32; off; off >>= 1) {
        sum += __shfl_xor(sum, off);
        sq  += __shfl_xor(sq, off);
    }
    __shared__ float red[8];
    int lane = tid & 63, wid = tid >> 6;
    if (lane == 0) { red[wid] = sum; red[4 + wid] = sq; }
    __syncthreads();
    sum = red[0] + red[1] + red[2] + red[3];
    sq  = red[4] + red[5] + red[6] + red[7];
    float mean = sum * (1.0f / Hh);
    float var  = sq * (1.0f / Hh) - mean * mean;
    float rstd = rsqrtf(var + 1e-12f);
    #pragma unroll
    for (int r = 0; r < 3; r++) {
        int h = tid + (r << 8);
        float v = (e[r] - mean) * rstd * g[h] + bp[h];
        xb[(size_t)tok * Hh + h] = f2bf(v);
    }
}

// ---------------------------------------------------------------------------
// 3. Residual(bf16, in-place) + 2 split-K bf16 partials + bias + LayerNorm
// ---------------------------------------------------------------------------
__global__ __launch_bounds__(256) void resid_ln2_kernel(
    ushort* __restrict__ xb, const ushort* __restrict__ p,  // [2][Mm][Hh] bf16
    const float* __restrict__ bias, const float* __restrict__ g,
    const float* __restrict__ bp)
{
    const size_t MHl = (size_t)Mm * Hh;
    int tok = blockIdx.x;
    int tid = threadIdx.x;
    float e[3];
    #pragma unroll
    for (int r = 0; r < 3; r++) {
        int h = tid + (r << 8);
        size_t idx = (size_t)tok * Hh + h;
        float acc = bf2f(xb[idx]) + bias[h];
        acc += bf2f(p[idx]);
        acc += bf2f(p[MHl + idx]);
        e[r] = acc;
    }
    float sum = e[0] + e[1] + e[2];
    float sq  = fmaf(e[0], e[0], fmaf(e[1], e[1], e[2] * e[2]));
    #pragma unroll
    for (int off = 32; off; off >>= 1) {
        sum += __shfl_xor(sum, off);
        sq  += __shfl_xor(sq, off);
    }
    __shared__ float red[8];
    int lane = tid & 63, wid = tid >> 6;
    if (lane == 0) { red[wid] = sum; red[4 + wid] = sq; }
    __syncthreads();
    sum = red[0] + red[1] + red[2] + red[3];
    sq  = red[4] + red[5] + red[6] + red[7];
    float mean = sum * (1.0f / Hh);
    float var  = sq * (1.0f / Hh) - mean * mean;
    float rstd = rsqrtf(var + 1e-12f);
    #pragma unroll
    for (int r = 0; r < 3; r++) {
        int h = tid + (r << 8);
        float v = (e[r] - mean) * rstd * g[h] + bp[h];
        xb[(size_t)tok * Hh + h] = f2bf(v);
    }
}

// ---------------------------------------------------------------------------
// 4. Fused per-layer weight prep: 4 HxH + HxF + FxH transposes + bias concat
// ---------------------------------------------------------------------------
__global__ __launch_bounds__(256) void prep_kernel(
    const float* __restrict__ Wq, const float* __restrict__ Wk,
    const float* __restrict__ Wv, const float* __restrict__ Wo,
    const float* __restrict__ W1, const float* __restrict__ W2,
    const float* __restrict__ bq, const float* __restrict__ bk,
    const float* __restrict__ bv,
    ushort* __restrict__ qkvoT, ushort* __restrict__ w1T,
    ushort* __restrict__ w2T, float* __restrict__ bqkv)
{
    int b = blockIdx.x;
    if (b >= 6912) {   // bias concat
        for (int j = threadIdx.x; j < Hh; j += 256) {
            bqkv[j]          = bq[j];
            bqkv[Hh + j]     = bk[j];
            bqkv[2 * Hh + j] = bv[j];
        }
        return;
    }
    const float* W;
    ushort* Wt;
    int K, N, n0, k0;
    if (b < 2304) {          // QKVO: 4 x 576 tiles of HxH
        int which = b / 576, t = b % 576;
        const float* srcs[4] = { Wq, Wk, Wv, Wo };
        W = srcs[which];
        Wt = qkvoT + (size_t)which * Hh * Hh;
        K = Hh; N = Hh;
        n0 = (t % 24) * 32; k0 = (t / 24) * 32;
    } else if (b < 4608) {   // W1: [Hh][Ff] -> w1T [Ff][Hh]
        int t = b - 2304;
        W = W1; Wt = w1T; K = Hh; N = Ff;
        n0 = (t % 96) * 32; k0 = (t / 96) * 32;
    } else {                 // W2: [Ff][Hh] -> w2T [Hh][Ff]
        int t = b - 4608;
        W = W2; Wt = w2T; K = Ff; N = Hh;
        n0 = (t % 24) * 32; k0 = (t / 24) * 32;
    }
    __shared__ float ts[32][33];
    int tx = threadIdx.x & 31, ty = threadIdx.x >> 5;
    #pragma unroll
    for (int i = 0; i < 32; i += 8)
        ts[ty + i][tx] = W[(size_t)(k0 + ty + i) * N + n0 + tx];
    __syncthreads();
    #pragma unroll
    for (int i = 0; i < 32; i += 8)
        Wt[(size_t)(n0 + ty + i) * K + k0 + tx] = f2bf(ts[tx][ty + i]);
}

// 4b. Padded transpose + bias pad for classifier
__global__ __launch_bounds__(256) void pad_transpose_kernel(
    const float* __restrict__ W, ushort* __restrict__ Wt, int K, int N)
{
    __shared__ float ts[32][33];
    int n0 = blockIdx.x * 32, k0 = blockIdx.y * 32;
    int tx = threadIdx.x & 31, ty = threadIdx.x >> 5;
    #pragma unroll
    for (int i = 0; i < 32; i += 8) {
        int n = n0 + tx;
        ts[ty + i][tx] = (n < N) ? W[(size_t)(k0 + ty + i) * N + n] : 0.f;
    }
    __syncthreads();
    #pragma unroll
    for (int i = 0; i < 32; i += 8)
        Wt[(size_t)(n0 + ty + i) * K + k0 + tx] = f2bf(ts[tx][ty + i]);
}

__global__ __launch_bounds__(256) void bias_pad_kernel(
    const float* __restrict__ cb, float* __restrict__ cbp)
{
    int i = blockIdx.x * 256 + threadIdx.x;
    if (i < VP) cbp[i] = (i < Vv) ? cb[i] : -1.0e9f;
}

// ---------------------------------------------------------------------------
// 5. bf16 MFMA GEMM (m97-pattern, BK=32), split-K via gridDim.z.
//    OUT_BF=1 writes bf16 (z-offset partials when gridDim.z>1);
//    OUT_BF=0 writes f32 with z-offset.
// ---------------------------------------------------------------------------
template <int ACT, int OUT_BF, int BIAS>
__global__ __launch_bounds__(256) void mfma_gemm(
    const ushort* __restrict__ A,
    const ushort* __restrict__ Bt,
    const float* __restrict__ bias,
    void* __restrict__ C,
    int N, int K, int lda, int ldb)
{
    __shared__ __align__(16) ushort As[128 * 32];
    __shared__ __align__(16) ushort Bs[128 * 32];
    const int tid = threadIdx.x;
    const int lane = tid & 63, wid = tid >> 6;
    const int m0 = blockIdx.y * 128, n0 = blockIdx.x * 128;
    const int kbase = blockIdx.z * K;
    const size_t zoff = (size_t)blockIdx.z * Mm * N;
    A += kbase;
    Bt += kbase;
    const int wr = (wid >> 1) * 64, wc = (wid & 1) * 64;
    const int lr = lane & 15;
    const int kg = (lane >> 4) << 3;

    f32x4 acc[4][4];
    #pragma unroll
    for (int mi = 0; mi < 4; ++mi)
        #pragma unroll
        for (int ni = 0; ni < 4; ++ni)
            acc[mi][ni] = (f32x4){0.f, 0.f, 0.f, 0.f};

    for (int k0 = 0; k0 < K; k0 += 32) {
        #pragma unroll
        for (int i = 0; i < 2; ++i) {
            int idx = i * 256 + tid;
            int r = idx >> 2, c = (idx & 3) << 3;
            __builtin_amdgcn_global_load_lds(
                (const __attribute__((address_space(1))) void*)(A + (size_t)(m0 + r) * lda + k0 + c),
                (__attribute__((address_space(3))) void*)(As + (size_t)(i * 256 + (wid << 6)) * 8),
                16, 0, 0);
        }
        #pragma unroll
        for (int i = 0; i < 2; ++i) {
            int idx = i * 256 + tid;
            int r = idx >> 2, c = (idx & 3) << 3;
            __builtin_amdgcn_global_load_lds(
                (const __attribute__((address_space(1))) void*)(Bt + (size_t)(n0 + r) * ldb + k0 + c),
                (__attribute__((address_space(3))) void*)(Bs + (size_t)(i * 256 + (wid << 6)) * 8),
                16, 0, 0);
        }
        __syncthreads();

        bf16x8 af[4], bfr[4];
        #pragma unroll
        for (int mi = 0; mi < 4; ++mi)
            af[mi] = *(const bf16x8*)(As + (size_t)(wr + mi * 16 + lr) * 32 + kg);
        #pragma unroll
        for (int ni = 0; ni < 4; ++ni)
            bfr[ni] = *(const bf16x8*)(Bs + (size_t)(wc + ni * 16 + lr) * 32 + kg);

        #pragma unroll
        for (int mi = 0; mi < 4; ++mi)
            #pragma unroll
            for (int ni = 0; ni < 4; ++ni)
                acc[mi][ni] = __builtin_amdgcn_mfma_f32_16x16x32_bf16(
                    af[mi], bfr[ni], acc[mi][ni], 0, 0, 0);
        __syncthreads();
    }

    #pragma unroll
    for (int ni = 0; ni < 4; ++ni) {
        int col = n0 + wc + ni * 16 + lr;
        float bsv = 0.f;
        if (BIAS) bsv = bias[col];
        #pragma unroll
        for (int mi = 0; mi < 4; ++mi) {
            f32x4 v = acc[mi][ni];
            #pragma unroll
            for (int q = 0; q < 4; ++q) {
                int row = m0 + wr + mi * 16 + ((lane >> 4) << 2) + q;
                float val = v[q] + bsv;
                if (ACT == 1) {
                    float y = 0.7978845608028654f
                              * (val + 0.044715f * val * val * val);
                    val = val / (1.0f + __expf(-2.0f * y));
                }
                if (OUT_BF)
                    ((ushort*)C)[zoff + (size_t)row * N + col] = f2bf(val);
                else
                    ((float*)C)[zoff + (size_t)row * N + col] = val;
            }
        }
    }
}

// ---------------------------------------------------------------------------
// 6. Fused MFMA flash attention (stride-72 conflict-free LDS)
// ---------------------------------------------------------------------------
constexpr int SP = 65;   // S_lds stride (f32)
constexpr int PS = 72;   // P_lds stride (u16)
constexpr int VS = 72;   // Vt_lds / K_lds stride (u16)

__global__ __launch_bounds__(256) void flash_attn_kernel(
    const ushort* __restrict__ qkv, const int* __restrict__ info,
    ushort* __restrict__ ctx)
{
    __shared__ __align__(16) ushort K_lds[64 * VS];
    __shared__ __align__(16) ushort Vt_lds[64 * VS];
    __shared__ __align__(16) ushort P_lds[64 * PS];
    __shared__ float S_lds[64 * SP];
    __shared__ float m_s[64], l_s[64], rf_s[64];

    const int tid = threadIdx.x;
    const int lane = tid & 63, wid = tid >> 6;
    const int bh = blockIdx.y, b = bh / NHh, h = bh % NHh;
    const int i0 = blockIdx.x * 64;
    const int lr = lane & 15, hi = lane >> 4;
    const int kg = hi << 3;
    const int wr = (wid >> 1) * 32;
    const int wc = (wid & 1) * 32;
    const int has = info[b * 4 + 1], sep = info[b * 4 + 2];
    const size_t tok0 = (size_t)b * Ss;

    bf16x8 qf[2][2];
    #pragma unroll
    for (int mi = 0; mi < 2; ++mi)
        #pragma unroll
        for (int kk = 0; kk < 2; ++kk)
            qf[mi][kk] = *(const bf16x8*)&qkv[(tok0 + i0 + wr + mi * 16 + lr) * QKVN
                                             + h * DHh + kk * 32 + kg];

    f32x4 o[2][2];
    #pragma unroll
    for (int mi = 0; mi < 2; ++mi)
        #pragma unroll
        for (int ni = 0; ni < 2; ++ni)
            o[mi][ni] = (f32x4){0.f, 0.f, 0.f, 0.f};

    if (tid < 64) { m_s[tid] = -3.0e38f; l_s[tid] = 0.f; }
    __syncthreads();

    for (int j0 = 0; j0 < Ss; j0 += 64) {
        #pragma unroll
        for (int i = 0; i < 2; ++i) {
            int ix = i * 256 + tid;
            int r = ix >> 3, c = (ix & 7) << 3;
            uint4 kq = *(const uint4*)&qkv[(tok0 + j0 + r) * QKVN + Hh + h * DHh + c];
            *(uint4*)&K_lds[(size_t)r * VS + c] = kq;
        }
        {
            int kv0 = (tid & 15) * 4;
            int d0 = (tid >> 4) * 4;
            uint2 rv[4];
            #pragma unroll
            for (int r = 0; r < 4; ++r)
                rv[r] = *(const uint2*)&qkv[(tok0 + j0 + kv0 + r) * QKVN
                                            + 2 * Hh + h * DHh + d0];
            #pragma unroll
            for (int c = 0; c < 4; ++c) {
                unsigned e0 = (c < 2) ? (rv[0].x >> (16 * c)) : (rv[0].y >> (16 * (c - 2)));
                unsigned e1 = (c < 2) ? (rv[1].x >> (16 * c)) : (rv[1].y >> (16 * (c - 2)));
                unsigned e2 = (c < 2) ? (rv[2].x >> (16 * c)) : (rv[2].y >> (16 * (c - 2)));
                unsigned e3 = (c < 2) ? (rv[3].x >> (16 * c)) : (rv[3].y >> (16 * (c - 2)));
                uint2 packed;
                packed.x = (e0 & 0xffffu) | (e1 << 16);
                packed.y = (e2 & 0xffffu) | (e3 << 16);
                *(uint2*)&Vt_lds[(size_t)(d0 + c) * VS + kv0] = packed;
            }
        }
        __syncthreads();

        f32x4 s[2][2];
        #pragma unroll
        for (int mi = 0; mi < 2; ++mi)
            #pragma unroll
            for (int ni = 0; ni < 2; ++ni)
                s[mi][ni] = (f32x4){0.f, 0.f, 0.f, 0.f};
        #pragma unroll
        for (int ni = 0; ni < 2; ++ni)
            #pragma unroll
            for (int kk = 0; kk < 2; ++kk) {
                bf16x8 kf = *(const bf16x8*)&K_lds[(size_t)(wc + ni * 16 + lr) * VS
                                                   + kk * 32 + kg];
                #pragma unroll
                for (int mi = 0; mi < 2; ++mi)
                    s[mi][ni] = __builtin_amdgcn_mfma_f32_16x16x32_bf16(
                        qf[mi][kk], kf, s[mi][ni], 0, 0, 0);
            }
        #pragma unroll
        for (int mi = 0; mi < 2; ++mi)
            #pragma unroll
            for (int ni = 0; ni < 2; ++ni)
                #pragma unroll
                for (int q = 0; q < 4; ++q) {
                    int rl = wr + mi * 16 + hi * 4 + q;
                    int cl = wc + ni * 16 + lr;
                    int gi = i0 + rl, gj = j0 + cl;
                    bool vis = (!has) || (gj <= sep) || ((gi > sep) && (gj <= gi));
                    S_lds[rl * SP + cl] = s[mi][ni][q] * 0.125f
                                          + (vis ? 0.0f : -1000000000.0f);
                }
        __syncthreads();

        {
            int r = tid >> 2, c0 = (tid & 3) * 16;
            float mold = m_s[r];
            float sv[16];
            float tmax = -3.0e38f;
            #pragma unroll
            for (int c = 0; c < 16; ++c) {
                sv[c] = S_lds[r * SP + c0 + c];
                tmax = fmaxf(tmax, sv[c]);
            }
            tmax = fmaxf(tmax, __shfl_xor(tmax, 1));
            tmax = fmaxf(tmax, __shfl_xor(tmax, 2));
            float mnew = fmaxf(mold, tmax);
            float sum = 0.f;
            #pragma unroll
            for (int c = 0; c < 16; ++c) {
                float p = __expf(sv[c] - mnew);
                P_lds[r * PS + c0 + c] = f2bf(p);
                sum += p;
            }
            sum += __shfl_xor(sum, 1);
            sum += __shfl_xor(sum, 2);
            if ((tid & 3) == 0) {
                float rf = __expf(mold - mnew);
                rf_s[r] = rf;
                l_s[r] = l_s[r] * rf + sum;
                m_s[r] = mnew;
            }
        }
        __syncthreads();

        #pragma unroll
        for (int mi = 0; mi < 2; ++mi)
            #pragma unroll
            for (int q = 0; q < 4; ++q) {
                float rf = rf_s[wr + mi * 16 + hi * 4 + q];
                #pragma unroll
                for (int ni = 0; ni < 2; ++ni)
                    o[mi][ni][q] *= rf;
            }
        #pragma unroll
        for (int kk = 0; kk < 2; ++kk) {
            bf16x8 pf[2];
            #pragma unroll
            for (int mi = 0; mi < 2; ++mi)
                pf[mi] = *(const bf16x8*)&P_lds[(size_t)(wr + mi * 16 + lr) * PS
                                                + kk * 32 + kg];
            #pragma unroll
            for (int ni = 0; ni < 2; ++ni) {
                bf16x8 vf = *(const bf16x8*)&Vt_lds[(size_t)(wc + ni * 16 + lr) * VS
                                                    + kk * 32 + kg];
                #pragma unroll
                for (int mi = 0; mi < 2; ++mi)
                    o[mi][ni] = __builtin_amdgcn_mfma_f32_16x16x32_bf16(
                        pf[mi], vf, o[mi][ni], 0, 0, 0);
            }
        }
        __syncthreads();
    }

    #pragma unroll
    for (int mi = 0; mi < 2; ++mi)
        #pragma unroll
        for (int q = 0; q < 4; ++q) {
            int rl = wr + mi * 16 + hi * 4 + q;
            float inv = 1.0f / l_s[rl];
            #pragma unroll
            for (int ni = 0; ni < 2; ++ni)
                ctx[(tok0 + i0 + rl) * Hh + h * DHh + wc + ni * 16 + lr]
                    = f2bf(o[mi][ni][q] * inv);
        }
}

// ---------------------------------------------------------------------------
// 7. Fused MFMA classifier, fixed-shift LSE. Grid (NCH=42, 32). BK=32.
// ---------------------------------------------------------------------------
__global__ __launch_bounds__(256) void cls_lse_kernel(
    const ushort* __restrict__ A,
    const ushort* __restrict__ WT,
    const float* __restrict__ cbp,
    const int* __restrict__ labels,
    float* __restrict__ psv, float* __restrict__ pll)
{
    __shared__ __align__(16) ushort As[128 * 32];
    __shared__ __align__(16) ushort Bs[128 * 32];
    __shared__ float ssum[2][128];
    __shared__ float sll[128];
    __shared__ int lab[128];
    const int tid = threadIdx.x;
    const int lane = tid & 63, wid = tid >> 6;
    const int m0 = blockIdx.y * 128;
    const int chunk = blockIdx.x;
    if (tid < 128) {
        sll[tid] = 0.f;
        lab[tid] = labels[m0 + tid];
    }
    const int wr = (wid >> 1) * 64, wcid = wid & 1, wc = wcid * 64;
    const int lr = lane & 15;
    const int hi = lane >> 4;
    const int kg = hi << 3;

    float sacc[16];
    #pragma unroll
    for (int i = 0; i < 16; ++i) sacc[i] = 0.f;

    for (int t = 0; t < TPC; ++t) {
        const int n0 = (chunk * TPC + t) * 128;
        f32x4 acc[4][4];
        #pragma unroll
        for (int mi = 0; mi < 4; ++mi)
            #pragma unroll
            for (int ni = 0; ni < 4; ++ni)
                acc[mi][ni] = (f32x4){0.f, 0.f, 0.f, 0.f};

        for (int k0 = 0; k0 < Hh; k0 += 32) {
            #pragma unroll
            for (int i = 0; i < 2; ++i) {
                int idx = i * 256 + tid;
                int r = idx >> 2, c = (idx & 3) << 3;
                __builtin_amdgcn_global_load_lds(
                    (const __attribute__((address_space(1))) void*)(A + (size_t)(m0 + r) * Hh + k0 + c),
                    (__attribute__((address_space(3))) void*)(As + (size_t)(i * 256 + (wid << 6)) * 8),
                    16, 0, 0);
            }
            #pragma unroll
            for (int i = 0; i < 2; ++i) {
                int idx = i * 256 + tid;
                int r = idx >> 2, c = (idx & 3) << 3;
                __builtin_amdgcn_global_load_lds(
                    (const __attribute__((address_space(1))) void*)(WT + (size_t)(n0 + r) * Hh + k0 + c),
                    (__attribute__((address_space(3))) void*)(Bs + (size_t)(i * 256 + (wid << 6)) * 8),
                    16, 0, 0);
            }
            __syncthreads();

            bf16x8 af[4], bfr[4];
            #pragma unroll
            for (int mi = 0; mi < 4; ++mi)
                af[mi] = *(const bf16x8*)(As + (size_t)(wr + mi * 16 + lr) * 32 + kg);
            #pragma unroll
            for (int ni = 0; ni < 4; ++ni)
                bfr[ni] = *(const bf16x8*)(Bs + (size_t)(wc + ni * 16 + lr) * 32 + kg);

            #pragma unroll
            for (int mi = 0; mi < 4; ++mi)
                #pragma unroll
                for (int ni = 0; ni < 4; ++ni)
                    acc[mi][ni] = __builtin_amdgcn_mfma_f32_16x16x32_bf16(
                        af[mi], bfr[ni], acc[mi][ni], 0, 0, 0);
            __syncthreads();
        }

        float bvs[4];
        int cols[4];
        #pragma unroll
        for (int ni = 0; ni < 4; ++ni) {
            cols[ni] = n0 + wc + ni * 16 + lr;
            bvs[ni] = cbp[cols[ni]];
        }
        #pragma unroll
        for (int mi = 0; mi < 4; ++mi) {
            #pragma unroll
            for (int q = 0; q < 4; ++q) {
                int rl = wr + mi * 16 + hi * 4 + q;
                float v0 = acc[mi][0][q] + bvs[0];
                float v1 = acc[mi][1][q] + bvs[1];
                float v2 = acc[mi][2][q] + bvs[2];
                float v3 = acc[mi][3][q] + bvs[3];
                int lb = lab[rl];
                if (lb == cols[0]) sll[rl] = v0;
                if (lb == cols[1]) sll[rl] = v1;
                if (lb == cols[2]) sll[rl] = v2;
                if (lb == cols[3]) sll[rl] = v3;
                sacc[mi * 4 + q] += __expf(v0 - LSE_SHIFT) + __expf(v1 - LSE_SHIFT)
                                  + __expf(v2 - LSE_SHIFT) + __expf(v3 - LSE_SHIFT);
            }
        }
    }

    #pragma unroll
    for (int mi = 0; mi < 4; ++mi) {
        #pragma unroll
        for (int q = 0; q < 4; ++q) {
            float s = sacc[mi * 4 + q];
            s += __shfl_xor(s, 1);
            s += __shfl_xor(s, 2);
            s += __shfl_xor(s, 4);
            s += __shfl_xor(s, 8);
            if (lr == 0) ssum[wcid][wr + mi * 16 + hi * 4 + q] = s;
        }
    }
    __syncthreads();
    if (tid < 128) {
        psv[(size_t)chunk * Mm + m0 + tid] = ssum[0][tid] + ssum[1][tid];
        pll[(size_t)chunk * Mm + m0 + tid] = sll[tid];
    }
}

// 7b. Merge chunk partials + masked per-sample mean (one block per batch)
__global__ __launch_bounds__(256) void cls_finish_kernel(
    const float* __restrict__ psv, const float* __restrict__ pll,
    const int* __restrict__ info, float* __restrict__ ps)
{
    int b = blockIdx.x, tid = threadIdx.x;
    int first = info[b * 4 + 0], has = info[b * 4 + 1];
    float sum = 0.f;
    #pragma unroll
    for (int rr = 0; rr < 2; ++rr) {
        int s = tid + rr * 256;
        int row = b * Ss + s;
        float sv = 0.f, l = 0.f;
        #pragma unroll 1
        for (int c = 0; c < NCH; ++c) {
            sv += psv[(size_t)c * Mm + row];
            l  += pll[(size_t)c * Mm + row];
        }
        float cev = (LSE_SHIFT + logf(sv)) - l;
        bool mv = has ? (s > first) : true;
        if (mv) sum += cev;
    }
    #pragma unroll
    for (int off = 32; off; off >>= 1) sum += __shfl_xor(sum, off);
    __shared__ float red[4];
    int lane = tid & 63, wid = tid >> 6;
    if (lane == 0) red[wid] = sum;
    __syncthreads();
    if (tid == 0) {
        float tot = red[0] + red[1] + red[2] + red[3];
        float cnt = has ? (float)(Ss - 1 - first) : (float)Ss;
        ps[b] = tot / cnt;
    }
}

__global__ void final_kernel(const float* __restrict__ ps, float* __restrict__ out)
{
    if (threadIdx.x == 0 && blockIdx.x == 0) {
        float t = 0.0f;
        #pragma unroll
        for (int b = 0; b < Bb; b++) t += ps[b];
        out[0] = t * (1.0f / Bb);
    }
}

// ---------------------------------------------------------------------------
// Host launcher
// ---------------------------------------------------------------------------
extern "C" void kernel_launch(void* const* d_in, const int* in_sizes, int n_in,
                              void* d_out, int out_size, void* d_ws, size_t ws_size,
                              hipStream_t stream)
{
    const int*   ids    = (const int*)d_in[0];
    const int*   labels = (const int*)d_in[1];
    const float* we     = (const float*)d_in[2];
    const float* pe     = (const float*)d_in[3];
    const float* te     = (const float*)d_in[4];
    const float* eg     = (const float*)d_in[5];
    const float* ebp    = (const float*)d_in[6];
    const float* Wq     = (const float*)d_in[7];
    const float* bq     = (const float*)d_in[8];
    const float* Wk     = (const float*)d_in[9];
    const float* bk     = (const float*)d_in[10];
    const float* Wv     = (const float*)d_in[11];
    const float* bv     = (const float*)d_in[12];
    const float* Wo     = (const float*)d_in[13];
    const float* bo     = (const float*)d_in[14];
    const float* l1g    = (const float*)d_in[15];
    const float* l1b    = (const float*)d_in[16];
    const float* W1     = (const float*)d_in[17];
    const float* b1     = (const float*)d_in[18];
    const float* W2     = (const float*)d_in[19];
    const float* b2     = (const float*)d_in[20];
    const float* l2g    = (const float*)d_in[21];
    const float* l2b    = (const float*)d_in[22];
    const float* cW     = (const float*)d_in[23];
    const float* cbias  = (const float*)d_in[24];

    const size_t MH  = (size_t)Mm * Hh;
    const size_t MF  = (size_t)Mm * Ff;
    const size_t HHe = (size_t)Hh * Hh;
    const size_t HFe = (size_t)Hh * Ff;

    // Workspace layout (~86 MB; proven >= 226.5 MB available)
    float* ws = (float*)d_ws;
    float* ps     = ws;                                // 16 f32
    int*   info   = (int*)(ps + 16);                   // 64 ints reserved
    float* bqkv   = (float*)(info + 64);               // 2304 f32
    ushort* tmpb  = (ushort*)(bqkv + QKVN);            // 2*MH bf16 split-K partials
    ushort* xb    = tmpb + 2 * MH;                     // MH bf16 (residual stream)
    ushort* qkvb  = xb + MH;                           // 3*MH bf16
    ushort* ctxb  = qkvb + 3 * MH;                     // MH
    ushort* f1b   = ctxb + MH;                         // MF
    ushort* wscr  = f1b + MF;                          // 4*HHe + 2*HFe bf16
    ushort* wqT = wscr;
    ushort* woT = wqT + 3 * HHe;                       // qkvoT[3] = Wo slot
    ushort* w1T = wscr + 4 * HHe;                      // [F][H]
    ushort* w2T = w1T + HFe;                           // [H][F]
    float* clsf = (float*)(w2T + HFe);
    float* cbp  = clsf;                                // VP
    float* psv  = cbp + VP;                            // NCH*Mm
    float* pll  = psv + (size_t)NCH * Mm;              // NCH*Mm
    ushort* cWT = qkvb;   // alias: qkvb..f1b (25.2M u16 > 16.5M needed) dead at cls

    sep_kernel<<<Bb, 512, 0, stream>>>(ids, info);
    embed_ln_kernel<<<Mm, 256, 0, stream>>>(ids, we, pe, te, eg, ebp, xb);

    dim3 gQKV(QKVN / 128, Mm / 128);          // (18, 32)
    dim3 gWo(Hh / 128, Mm / 128, 2);          // (6, 32, 2) split-K (K=384/chunk)
    dim3 gF(Ff / 128, Mm / 128);              // (24, 32)
    dim3 gW2(Hh / 128, Mm / 128, 2);          // (6, 32, 2) split-K (K=1536/chunk)
    dim3 gA(Ss / 64, Bb * NHh);               // (8, 96)

    for (int l = 0; l < Ll; l++) {
        const float* bo_l = bo + (size_t)l * Hh;
        const float* b1_l = b1 + (size_t)l * Ff;
        const float* b2_l = b2 + (size_t)l * Hh;
        const float* g1  = l1g + (size_t)l * Hh;
        const float* be1 = l1b + (size_t)l * Hh;
        const float* g2  = l2g + (size_t)l * Hh;
        const float* be2 = l2b + (size_t)l * Hh;

        prep_kernel<<<6913, 256, 0, stream>>>(
            Wq + (size_t)l * HHe, Wk + (size_t)l * HHe,
            Wv + (size_t)l * HHe, Wo + (size_t)l * HHe,
            W1 + (size_t)l * HFe, W2 + (size_t)l * HFe,
            bq + (size_t)l * Hh, bk + (size_t)l * Hh, bv + (size_t)l * Hh,
            wscr, w1T, w2T, bqkv);

        // Fused QKV projection: [M][768] @ [2304][768]^T -> [M][2304]
        mfma_gemm<0, 1, 1><<<gQKV, 256, 0, stream>>>(xb, wqT, bqkv, qkvb,
                                                     QKVN, Hh, Hh, Hh);

        flash_attn_kernel<<<gA, 256, 0, stream>>>(qkvb, info, ctxb);

        // Wo projection split-K x2: bf16 partials in tmpb, bias folded into LN
        mfma_gemm<0, 1, 0><<<gWo, 256, 0, stream>>>(ctxb, woT, nullptr, tmpb,
                                                    Hh, Hh / 2, Hh, Hh);
        resid_ln2_kernel<<<Mm, 256, 0, stream>>>(xb, tmpb, bo_l, g1, be1);

        mfma_gemm<1, 1, 1><<<gF, 256, 0, stream>>>(xb, w1T, b1_l, f1b,
                                                   Ff, Hh, Hh, Hh);
        // FFN2 split-K x2: bf16 partials in tmpb
        mfma_gemm<0, 1, 0><<<gW2, 256, 0, stream>>>(f1b, w2T, nullptr, tmpb,
                                                    Hh, Ff / 2, Ff, Ff);
        resid_ln2_kernel<<<Mm, 256, 0, stream>>>(xb, tmpb, b2_l, g2, be2);
    }

    // Classifier
    pad_transpose_kernel<<<dim3(VP / 32, Hh / 32), 256, 0, stream>>>(cW, cWT, Hh, Vv);
    bias_pad_kernel<<<(VP + 255) / 256, 256, 0, stream>>>(cbias, cbp);
    cls_lse_kernel<<<dim3(NCH, Mm / 128), 256, 0, stream>>>(
        xb, cWT, cbp, labels, psv, pll);
    cls_finish_kernel<<<Bb, 256, 0, stream>>>(psv, pll, info, ps);
    final_kernel<<<1, 64, 0, stream>>>(ps, (float*)d_out);
}